// Round 5
// baseline (3632.063 us; speedup 1.0000x reference)
//
#include <hip/hip_runtime.h>
#include <cstdint>
#include <cstddef>

#define NEGV -1000000000.0f

// ---------- fast device math (fp32, argmax-safe) ----------
__device__ __forceinline__ float fsigm(float x) {
  return 1.0f / (1.0f + __expf(-x));
}
__device__ __forceinline__ float ftanh(float x) {
  x = fminf(x, 30.0f);
  const float e = __expf(2.0f * x);
  return (e - 1.0f) / (e + 1.0f);
}

// ---------------------------------------------------------------------------
// Fused setup GEMM: all three context projections in one pass (shared A).
// A[32768][256] fp32 (context natural layout [l*512+b][h]),
// W3[768][256] = rows {Wrg | Wrp | Wgp}, b3[768] = {brg | brp | bgp}.
// grid(256,4): M-tile fast dim -> N-tiles sharing an A-panel land on the
// same XCD (L2 hit). Register double-buffered K-loop (r3-verified pattern).
// ---------------------------------------------------------------------------
__global__ __launch_bounds__(256, 2) void gemm3_k(
    const float* __restrict__ A0, const float* __restrict__ W3,
    const float* __restrict__ b3, float* __restrict__ Cg,
    float* __restrict__ Cp, float* __restrict__ Cq)
{
  __shared__ float As[16][136];     // [k][m]
  __shared__ float Ws[3][16][72];   // [s][k][n]
  const int bm = blockIdx.x << 7;   // fast dim
  const int bn = blockIdx.y << 6;
  const int t  = threadIdx.x;
  const int ty = t >> 4, tx = t & 15;
  const int ar = t >> 1, ac = (t & 1) << 3;   // A staging: 2 float4
  const int wr = t >> 2, wc = (t & 3) << 2;   // W staging: 1 float4 per s
  const float* arow = A0 + (size_t)(bm + ar) * 256 + ac;
  const float* w0row = W3 + (size_t)(bn + wr) * 256 + wc;
  const float* w1row = W3 + (size_t)(256 + bn + wr) * 256 + wc;
  const float* w2row = W3 + (size_t)(512 + bn + wr) * 256 + wc;
  float acc[3][8][4] = {};
  float4 a0 = *(const float4*)(arow + 0);
  float4 a1 = *(const float4*)(arow + 4);
  float4 wv0 = *(const float4*)(w0row + 0);
  float4 wv1 = *(const float4*)(w1row + 0);
  float4 wv2 = *(const float4*)(w2row + 0);
  for (int k0 = 0; k0 < 256; k0 += 16) {
    As[ac + 0][ar] = a0.x; As[ac + 1][ar] = a0.y; As[ac + 2][ar] = a0.z; As[ac + 3][ar] = a0.w;
    As[ac + 4][ar] = a1.x; As[ac + 5][ar] = a1.y; As[ac + 6][ar] = a1.z; As[ac + 7][ar] = a1.w;
    Ws[0][wc + 0][wr] = wv0.x; Ws[0][wc + 1][wr] = wv0.y;
    Ws[0][wc + 2][wr] = wv0.z; Ws[0][wc + 3][wr] = wv0.w;
    Ws[1][wc + 0][wr] = wv1.x; Ws[1][wc + 1][wr] = wv1.y;
    Ws[1][wc + 2][wr] = wv1.z; Ws[1][wc + 3][wr] = wv1.w;
    Ws[2][wc + 0][wr] = wv2.x; Ws[2][wc + 1][wr] = wv2.y;
    Ws[2][wc + 2][wr] = wv2.z; Ws[2][wc + 3][wr] = wv2.w;
    __syncthreads();
    if (k0 < 240) {
      a0  = *(const float4*)(arow + k0 + 16);
      a1  = *(const float4*)(arow + k0 + 20);
      wv0 = *(const float4*)(w0row + k0 + 16);
      wv1 = *(const float4*)(w1row + k0 + 16);
      wv2 = *(const float4*)(w2row + k0 + 16);
    }
#pragma unroll
    for (int k = 0; k < 16; ++k) {
      const float4 a0v = *(const float4*)&As[k][ty << 3];
      const float4 a1v = *(const float4*)&As[k][(ty << 3) + 4];
      const float am[8] = {a0v.x, a0v.y, a0v.z, a0v.w, a1v.x, a1v.y, a1v.z, a1v.w};
#pragma unroll
      for (int s = 0; s < 3; ++s) {
        const float4 wv = *(const float4*)&Ws[s][k][tx << 2];
#pragma unroll
        for (int i = 0; i < 8; ++i) {
          acc[s][i][0] += am[i] * wv.x;
          acc[s][i][1] += am[i] * wv.y;
          acc[s][i][2] += am[i] * wv.z;
          acc[s][i][3] += am[i] * wv.w;
        }
      }
    }
    __syncthreads();
  }
  const int cn = bn + (tx << 2);
  const float4 bg = *(const float4*)(b3 + cn);
  const float4 bp = *(const float4*)(b3 + 256 + cn);
  const float4 bq = *(const float4*)(b3 + 512 + cn);
#pragma unroll
  for (int i = 0; i < 8; ++i) {
    const size_t row = ((size_t)(bm + (ty << 3) + i)) << 8;
    float4 o;
    o.x = acc[0][i][0] + bg.x; o.y = acc[0][i][1] + bg.y;
    o.z = acc[0][i][2] + bg.z; o.w = acc[0][i][3] + bg.w;
    *(float4*)(Cg + row + cn) = o;
    o.x = acc[1][i][0] + bp.x; o.y = acc[1][i][1] + bp.y;
    o.z = acc[1][i][2] + bp.z; o.w = acc[1][i][3] + bp.w;
    *(float4*)(Cp + row + cn) = o;
    o.x = acc[2][i][0] + bq.x; o.y = acc[2][i][1] + bq.y;
    o.z = acc[2][i][2] + bq.z; o.w = acc[2][i][3] + bq.w;
    *(float4*)(Cq + row + cn) = o;
  }
}

// ---------------------------------------------------------------------------
// gates GEMM (M=512, N=1024 interleaved i,f,g,o per unit, K=512 = [x|h])
// + fused LSTM epilogue. BM=16, BN=64, BK=32 -> 512 blocks (2/CU).
// (exact round-2-verified version; c updated in place)
// ---------------------------------------------------------------------------
__global__ __launch_bounds__(256) void gates_lstm_k(
    const float* __restrict__ x, const float* __restrict__ hin,
    const float* __restrict__ Wcat, const float* __restrict__ bcat,
    float* __restrict__ cbuf, float* __restrict__ hnew)
{
  __shared__ __align__(16) float As[16][36];   // [m][k]
  __shared__ __align__(16) float Ws[32][68];   // [k][n]
  const int bn = blockIdx.x << 6;
  const int bm = blockIdx.y << 4;
  const int t  = threadIdx.x;
  const int ty = t >> 4, tx = t & 15;
  const int ar = t >> 4, ak = (t & 15) << 1;   // A staging: one float2
  const int wr = t >> 2, wk = (t & 3) << 3;    // W staging: two float4
  const float* wrow = Wcat + ((size_t)(bn + wr) << 9);
  const int arow = bm + ar;
  float acc0 = 0.f, acc1 = 0.f, acc2 = 0.f, acc3 = 0.f;
  for (int k0 = 0; k0 < 512; k0 += 32) {
    const int kk = k0 + ak;
    float2 av;
    if (kk < 256) av = *(const float2*)(x   + ((size_t)arow << 8) + kk);
    else          av = *(const float2*)(hin + ((size_t)arow << 8) + (kk - 256));
    const float4 w0 = *(const float4*)(wrow + k0 + wk);
    const float4 w1 = *(const float4*)(wrow + k0 + wk + 4);
    *(float2*)&As[ar][ak] = av;
    Ws[wk + 0][wr] = w0.x; Ws[wk + 1][wr] = w0.y; Ws[wk + 2][wr] = w0.z; Ws[wk + 3][wr] = w0.w;
    Ws[wk + 4][wr] = w1.x; Ws[wk + 5][wr] = w1.y; Ws[wk + 6][wr] = w1.z; Ws[wk + 7][wr] = w1.w;
    __syncthreads();
#pragma unroll
    for (int k = 0; k < 32; ++k) {
      const float a  = As[ty][k];
      const float4 w = *(const float4*)&Ws[k][tx << 2];
      acc0 += a * w.x; acc1 += a * w.y; acc2 += a * w.z; acc3 += a * w.w;
    }
    __syncthreads();
  }
  const float4 bb = *(const float4*)(bcat + bn + (tx << 2));
  const int jc = (bn >> 2) + tx;
  const int m  = bm + ty;
  const float ig = fsigm(acc0 + bb.x);
  const float fg = fsigm(acc1 + bb.y);
  const float gg = ftanh(acc2 + bb.z);
  const float og = fsigm(acc3 + bb.w);
  const float c  = fg * cbuf[(m << 8) + jc] + ig * gg;
  const float h  = og * ftanh(c);
  cbuf[(m << 8) + jc] = c;
  hnew[(m << 8) + jc] = h;
}

// ---------------------------------------------------------------------------
// Per-step qg GEMM: qg_all[b][o] = qcour[b][o] + sum_k Wq1[o][k] * h[b][k].
// Weights read once per block panel (not once per b) -- removes the 128 MB/
// step L2 matvec stream from the attention kernel. Wq1 read directly from
// Wfused rows (stride 320, cols 0..255). k-ascending FMA chain per output.
// BM=16, BN=64, BK=32, grid(4,32)=128 blocks.
// ---------------------------------------------------------------------------
__global__ __launch_bounds__(256) void qg_gemm_k(
    const float* __restrict__ h, const float* __restrict__ Wf,
    const float* __restrict__ qcour, float* __restrict__ qg_all)
{
  __shared__ __align__(16) float As[16][36];   // [m][k]
  __shared__ __align__(16) float Ws[32][68];   // [k][n]
  const int bn = blockIdx.x << 6;
  const int bm = blockIdx.y << 4;
  const int t  = threadIdx.x;
  const int ty = t >> 4, tx = t & 15;
  const int ar = t >> 4, ak = (t & 15) << 1;   // A staging: one float2
  const int wr = t >> 2, wk = (t & 3) << 3;    // W staging: two float4
  const float* wrow = Wf + (size_t)(bn + wr) * 320;
  const int arow = bm + ar;
  const int m  = bm + ty;
  const int cn = bn + (tx << 2);
  float4 acc = *(const float4*)(qcour + ((size_t)m << 8) + cn);
  for (int k0 = 0; k0 < 256; k0 += 32) {
    const float2 av = *(const float2*)(h + ((size_t)arow << 8) + k0 + ak);
    const float4 w0 = *(const float4*)(wrow + k0 + wk);
    const float4 w1 = *(const float4*)(wrow + k0 + wk + 4);
    *(float2*)&As[ar][ak] = av;
    Ws[wk + 0][wr] = w0.x; Ws[wk + 1][wr] = w0.y; Ws[wk + 2][wr] = w0.z; Ws[wk + 3][wr] = w0.w;
    Ws[wk + 4][wr] = w1.x; Ws[wk + 5][wr] = w1.y; Ws[wk + 6][wr] = w1.z; Ws[wk + 7][wr] = w1.w;
    __syncthreads();
#pragma unroll
    for (int k = 0; k < 32; ++k) {
      const float a  = As[ty][k];
      const float4 w = *(const float4*)&Ws[k][tx << 2];
      acc.x += a * w.x; acc.y += a * w.y; acc.z += a * w.z; acc.w += a * w.w;
    }
    __syncthreads();
  }
  *(float4*)(qg_all + ((size_t)m << 8) + cn) = acc;
}

// ---------------------------------------------------------------------------
// Fused per-step attention, all fp32, ZERO weight traffic.
// qg precomputed (qg_gemm_k); qp via precomputed Eg2 (round-0-verified path):
// qp[o] = sum_l p_l * Eg2[l,b,o]. One block of 512 threads per batch row b.
// ---------------------------------------------------------------------------
__global__ __launch_bounds__(512) void step_attn_k(
    const float* __restrict__ qg_all, const float* __restrict__ e2g,
    const float* __restrict__ e2p, const float* __restrict__ Eg2,
    const float* __restrict__ vg, const float* __restrict__ vp,
    unsigned long long* __restrict__ mask, int* __restrict__ idxb,
    const float* __restrict__ emb, float* __restrict__ out_logp,
    float* __restrict__ out_sel, float* __restrict__ xb, int t)
{
  const int b = blockIdx.x, tid = threadIdx.x;
  __shared__ __align__(16) float qgs[256], qps[256], vgs[256], vps[256];
  __shared__ float us[64], ps[64];
  __shared__ unsigned long long ms;
  __shared__ int bsel;
  if (tid < 256) {
    qgs[tid] = qg_all[(b << 8) + tid];
    vgs[tid] = vg[tid];
    vps[tid] = vp[tid];
  }
  if (tid == 0) {
    unsigned long long m = mask[b];
    if (t > 0) {
      int s = idxb[b]; if (s < 0) s = 0;
      m |= (1ULL << s);
      if (m == ~0ULL) m &= ~(1ULL << 63);
      mask[b] = m;
    }
    ms = m;
  }
  __syncthreads();
  const unsigned long long mm = ms;
  const int w = tid >> 6, lane = tid & 63;

  // scores_g over e2g -> us
  {
    const float4 q4 = *(const float4*)&qgs[lane << 2];
    const float4 v4 = *(const float4*)&vgs[lane << 2];
    const float* ebase = e2g + ((size_t)b << 8) + (lane << 2);
    for (int li = 0; li < 8; ++li) {
      const int l = (w << 3) + li;
      const float4 e4 = *(const float4*)(ebase + ((size_t)l << 17));
      float s = v4.x * ftanh(q4.x + e4.x) + v4.y * ftanh(q4.y + e4.y)
              + v4.z * ftanh(q4.z + e4.z) + v4.w * ftanh(q4.w + e4.w);
#pragma unroll
      for (int off = 32; off; off >>= 1) s += __shfl_xor(s, off, 64);
      if (lane == 0) us[l] = ((mm >> l) & 1ULL) ? NEGV : s;
    }
  }
  __syncthreads();
  // softmax_g (plain, round-0-identical)
  if (tid < 64) {
    const float xv = us[tid];
    float mx = xv;
#pragma unroll
    for (int off = 32; off; off >>= 1) mx = fmaxf(mx, __shfl_xor(mx, off, 64));
    const float ev = __expf(xv - mx);
    float sum = ev;
#pragma unroll
    for (int off = 32; off; off >>= 1) sum += __shfl_xor(sum, off, 64);
    ps[tid] = ev / sum;
  }
  __syncthreads();

  // qp[o] = sum_l ps[l] * Eg2[l,b,o]   (bias pre-folded into Eg2)
  if (tid < 256) {
    float aq = 0.f;
    const float* ec = Eg2 + ((size_t)b << 8) + tid;
#pragma unroll 8
    for (int l = 0; l < 64; ++l) aq += ps[l] * ec[(size_t)l << 17];
    qps[tid] = aq;
  }
  __syncthreads();

  // scores_p over e2p, 10*tanh, mask -> us
  {
    const float4 q4 = *(const float4*)&qps[lane << 2];
    const float4 v4 = *(const float4*)&vps[lane << 2];
    const float* ebase = e2p + ((size_t)b << 8) + (lane << 2);
    for (int li = 0; li < 8; ++li) {
      const int l = (w << 3) + li;
      const float4 e4 = *(const float4*)(ebase + ((size_t)l << 17));
      float s = v4.x * ftanh(q4.x + e4.x) + v4.y * ftanh(q4.y + e4.y)
              + v4.z * ftanh(q4.z + e4.z) + v4.w * ftanh(q4.w + e4.w);
#pragma unroll
      for (int off = 32; off; off >>= 1) s += __shfl_xor(s, off, 64);
      if (lane == 0) us[l] = ((mm >> l) & 1ULL) ? NEGV : 10.0f * ftanh(s);
    }
  }
  __syncthreads();
  if (tid < 64) {
    const float xv = us[tid];
    float mx = xv;
#pragma unroll
    for (int off = 32; off; off >>= 1) mx = fmaxf(mx, __shfl_xor(mx, off, 64));
    const float sh = xv - mx;
    const float ev = __expf(sh);
    float sum = ev;
#pragma unroll
    for (int off = 32; off; off >>= 1) sum += __shfl_xor(sum, off, 64);
    const float lp = sh - __logf(sum);
    out_logp[((size_t)b << 12) + (t << 6) + tid] = lp;
    float bv = lp; int bi = tid;
#pragma unroll
    for (int off = 32; off; off >>= 1) {
      const float ov = __shfl_xor(bv, off, 64);
      const int   oi = __shfl_xor(bi, off, 64);
      if (ov > bv || (ov == bv && oi < bi)) { bv = ov; bi = oi; }
    }
    if (tid == 0) { idxb[b] = bi; out_sel[(b << 6) + t] = (float)bi; bsel = bi; }
  }
  __syncthreads();
  if (tid < 256) xb[(b << 8) + tid] = emb[(((size_t)(bsel << 9) + b) << 8) + tid];
}

// ---------------------------------------------------------------------------
// setup kernels
// ---------------------------------------------------------------------------
__global__ __launch_bounds__(256) void init_k(
    const float* __restrict__ dec, const float* __restrict__ h0,
    const float* __restrict__ c0, float* __restrict__ xb,
    float* __restrict__ hb, float* __restrict__ cb,
    unsigned long long* __restrict__ mask, int* __restrict__ idxb)
{
  const int i = blockIdx.x * 256 + threadIdx.x;
  xb[i] = dec[i]; hb[i] = h0[i]; cb[i] = c0[i];
  if (i < 512) { mask[i] = 0ULL; idxb[i] = -1; }
}

// Wcat[n][k], n=4*j+p interleaved (p in {i,f,g,o}), k = [x-part | h-part]
__global__ __launch_bounds__(256) void prep_wcat_k(
    const float* __restrict__ Wih, const float* __restrict__ Whh,
    const float* __restrict__ bih, const float* __restrict__ bhh,
    float* __restrict__ Wcat, float* __restrict__ bcat)
{
  const int id = blockIdx.x * 256 + threadIdx.x;
  const int n = id >> 9, k = id & 511;
  const int r = ((n & 3) << 8) + (n >> 2);
  Wcat[id] = (k < 256) ? Wih[(r << 8) + k] : Whh[(r << 8) + (k - 256)];
  if (id < 1024) {
    const int rr = ((id & 3) << 8) + (id >> 2);
    bcat[id] = bih[rr] + bhh[rr];
  }
}

// Wfused = Wq_g @ Wm (256x320), bfused = Wq_g @ bm + bq_g
__global__ __launch_bounds__(256) void prep_wfused_k(
    const float* __restrict__ Wqg, const float* __restrict__ Wm,
    const float* __restrict__ bm, const float* __restrict__ bqg,
    float* __restrict__ Wf, float* __restrict__ bf)
{
  const int id = blockIdx.x * 256 + threadIdx.x;  // 81920
  const int o = id / 320, j = id % 320;
  float acc = 0.f;
  for (int tt = 0; tt < 256; ++tt) acc += Wqg[(o << 8) + tt] * Wm[tt * 320 + j];
  Wf[id] = acc;
  if (id < 256) {
    float a2 = 0.f;
    for (int tt = 0; tt < 256; ++tt) a2 += Wqg[(id << 8) + tt] * bm[tt];
    bf[id] = a2 + bqg[id];
  }
}

// qcour[b,o] = bfused[o] + sum_{k<64} Wfused[o][256+k] * cour[b][k]
__global__ __launch_bounds__(256) void prep_qcour_k(
    const float* __restrict__ Wf, const float* __restrict__ bf,
    const float* __restrict__ cour, float* __restrict__ qcour)
{
  const int b = blockIdx.x, o = threadIdx.x;
  __shared__ float cs[64];
  if (o < 64) cs[o] = cour[(b << 6) + o];
  __syncthreads();
  float acc = bf[o];
#pragma unroll 8
  for (int k = 0; k < 64; ++k) acc += Wf[o * 320 + 256 + k] * cs[k];
  qcour[(b << 8) + o] = acc;
}

// W3 rows 0..255 = Wrg, rows 256..511 = Wrp; b3 = {brg | brp | (bgp later)}
__global__ __launch_bounds__(256) void prep_w3copy_k(
    const float* __restrict__ Wrg, const float* __restrict__ Wrp,
    const float* __restrict__ brg, const float* __restrict__ brp,
    float* __restrict__ W3, float* __restrict__ b3)
{
  const int id = blockIdx.x * 256 + threadIdx.x;   // 131072
  W3[id] = (id < 65536) ? Wrg[id] : Wrp[id - 65536];
  if (id < 256) b3[id] = brg[id];
  else if (id < 512) b3[id] = brp[id - 256];
}

// Wgp = Wqp @ Wrg (256x256) -> W3 rows 512..767
__global__ __launch_bounds__(256) void prep_wgp_k(
    const float* __restrict__ Wqp, const float* __restrict__ Wrg,
    float* __restrict__ Wgp)
{
  const int o = blockIdx.x, k = threadIdx.x;
  float acc = 0.f;
#pragma unroll 8
  for (int tt = 0; tt < 256; ++tt) acc += Wqp[(o << 8) + tt] * Wrg[(tt << 8) + k];
  Wgp[(o << 8) + k] = acc;
}

// bgp = Wqp @ brg + bqp -> b3[512..767]
__global__ __launch_bounds__(256) void prep_bgp_k(
    const float* __restrict__ Wqp, const float* __restrict__ brg,
    const float* __restrict__ bqp, float* __restrict__ bgp)
{
  const int o = threadIdx.x;
  float acc = bqp[o];
  for (int tt = 0; tt < 256; ++tt) acc += Wqp[(o << 8) + tt] * brg[tt];
  bgp[o] = acc;
}

// ---------------------------------------------------------------------------
extern "C" void kernel_launch(void* const* d_in, const int* in_sizes, int n_in,
                              void* d_out, int out_size, void* d_ws, size_t ws_size,
                              hipStream_t stream)
{
  const float* dec   = (const float*)d_in[0];
  const float* emb   = (const float*)d_in[1];
  const float* h0    = (const float*)d_in[2];
  const float* c0    = (const float*)d_in[3];
  const float* ctxin = (const float*)d_in[4];
  const float* cour  = (const float*)d_in[5];
  const float* Wih   = (const float*)d_in[7];
  const float* Whh   = (const float*)d_in[8];
  const float* bih   = (const float*)d_in[9];
  const float* bhh   = (const float*)d_in[10];
  const float* Wm    = (const float*)d_in[11];
  const float* bm    = (const float*)d_in[12];
  const float* Wqp   = (const float*)d_in[13];
  const float* bqp   = (const float*)d_in[14];
  const float* Wrp   = (const float*)d_in[15];
  const float* brp   = (const float*)d_in[16];
  const float* vp    = (const float*)d_in[17];
  const float* Wqg   = (const float*)d_in[18];
  const float* bqg   = (const float*)d_in[19];
  const float* Wrg   = (const float*)d_in[20];
  const float* brg   = (const float*)d_in[21];
  const float* vg    = (const float*)d_in[22];

  float* ws = (float*)d_ws;
  float* e2g    = ws + 0;         // 8388608
  float* e2p    = ws + 8388608;   // 8388608
  float* Eg2    = ws + 16777216;  // 8388608
  float* W3     = ws + 25165824;  // 196608 (dead after gemm3; hb0 overlays)
  float* b3     = ws + 25362432;  // 768
  float* Wcat   = ws + 25363200;  // 524288
  float* bcat   = ws + 25887488;  // 1024
  float* Wfused = ws + 25888512;  // 81920 (live all steps: qg_gemm weights)
  float* bfused = ws + 25970432;  // 256
  float* qcour  = ws + 25970688;  // 131072
  float* qg_all = ws + 26101760;  // 131072
  float* hb0    = ws + 25165824;  // 131072 (overlays W3 rows 0..511; written
                                  //          by init_k AFTER gemm3 consumed W3)
  float* hb1    = ws + 26232832;  // 131072
  float* cb     = ws + 26363904;  // 131072 (in-place c)
  float* xb     = ws + 26494976;  // 131072
  unsigned long long* maskb = (unsigned long long*)(ws + 26626048); // 512 u64
  int* idxb     = (int*)(ws + 26627072);                            // 512

  float* out_logp = (float*)d_out;            // [B][64][64]
  float* out_sel  = (float*)d_out + 2097152;  // [B][64]

  // ---- setup (order matters: gemm3 reads W3 before init_k overlays hb0) ----
  prep_wcat_k<<<2048, 256, 0, stream>>>(Wih, Whh, bih, bhh, Wcat, bcat);
  prep_wfused_k<<<320, 256, 0, stream>>>(Wqg, Wm, bm, bqg, Wfused, bfused);
  prep_qcour_k<<<512, 256, 0, stream>>>(Wfused, bfused, cour, qcour);
  prep_w3copy_k<<<512, 256, 0, stream>>>(Wrg, Wrp, brg, brp, W3, b3);
  prep_wgp_k<<<256, 256, 0, stream>>>(Wqp, Wrg, W3 + 131072);
  prep_bgp_k<<<1, 256, 0, stream>>>(Wqp, brg, bqp, b3 + 512);
  gemm3_k<<<dim3(256, 4), 256, 0, stream>>>(ctxin, W3, b3, e2g, e2p, Eg2);
  init_k<<<512, 256, 0, stream>>>(dec, h0, c0, xb, hb0, cb, maskb, idxb);

  // ---- 64 sequential steps, 3 kernels each ----
  for (int t = 0; t < 64; ++t) {
    float* hcur = (t & 1) ? hb1 : hb0;
    float* hnew = (t & 1) ? hb0 : hb1;
    gates_lstm_k<<<dim3(16, 32), 256, 0, stream>>>(xb, hcur, Wcat, bcat,
                                                   cb, hnew);
    qg_gemm_k<<<dim3(4, 32), 256, 0, stream>>>(hnew, Wfused, qcour, qg_all);
    step_attn_k<<<512, 512, 0, stream>>>(qg_all, e2g, e2p, Eg2, vg, vp,
                                         maskb, idxb, emb,
                                         out_logp, out_sel, xb, t);
  }
}

// Round 6
// 3383.237 us; speedup vs baseline: 1.0735x; 1.0735x over previous
//
#include <hip/hip_runtime.h>
#include <cstdint>
#include <cstddef>

#define NEGV -1000000000.0f

// ---------- fast device math (fp32, argmax-safe) ----------
__device__ __forceinline__ float fsigm(float x) {
  return 1.0f / (1.0f + __expf(-x));
}
__device__ __forceinline__ float ftanh(float x) {
  x = fminf(x, 30.0f);
  const float e = __expf(2.0f * x);
  return (e - 1.0f) / (e + 1.0f);
}

// async global->LDS (gfx950): 64 lanes x 16B per issue; LDS dest is
// wave-uniform base + lane*16; global src is per-lane.
#define GLOAD_LDS16(gp, lp)                                             \
  __builtin_amdgcn_global_load_lds(                                     \
      (__attribute__((address_space(1))) void*)(gp),                    \
      (__attribute__((address_space(3))) void*)(lp), 16, 0, 0)

// ---------------------------------------------------------------------------
// Fused setup GEMM: both context projections in one pass (shared A reads).
// grid(256,4): blockIdx.x = M-tile (fast dim) so the 4 N-tiles sharing one
// A-panel land on the same XCD -> L2 hit. Register double-buffered K-loop.
// (verified round 3/4: 115 us, FETCH 58 MB)
// ---------------------------------------------------------------------------
__global__ __launch_bounds__(256, 2) void gemm2_k(
    const float* __restrict__ A0, const float* __restrict__ W2,
    const float* __restrict__ b2, float* __restrict__ Cg,
    float* __restrict__ Cp)
{
  __shared__ float As[16][136];     // [k][m]
  __shared__ float Ws[2][16][72];   // [s][k][n]
  const int bm = blockIdx.x << 7;   // fast dim
  const int bn = blockIdx.y << 6;
  const int t  = threadIdx.x;
  const int ty = t >> 4, tx = t & 15;
  const int ar = t >> 1, ac = (t & 1) << 3;   // A staging: 2 float4
  const int wr = t >> 2, wc = (t & 3) << 2;   // W staging: 1 float4 per s
  const float* arow = A0 + (size_t)(bm + ar) * 256 + ac;
  const float* w0row = W2 + (size_t)(bn + wr) * 256 + wc;
  const float* w1row = W2 + (size_t)(256 + bn + wr) * 256 + wc;
  float acc[2][8][4] = {};
  float4 a0 = *(const float4*)(arow + 0);
  float4 a1 = *(const float4*)(arow + 4);
  float4 wv0 = *(const float4*)(w0row + 0);
  float4 wv1 = *(const float4*)(w1row + 0);
  for (int k0 = 0; k0 < 256; k0 += 16) {
    As[ac + 0][ar] = a0.x; As[ac + 1][ar] = a0.y; As[ac + 2][ar] = a0.z; As[ac + 3][ar] = a0.w;
    As[ac + 4][ar] = a1.x; As[ac + 5][ar] = a1.y; As[ac + 6][ar] = a1.z; As[ac + 7][ar] = a1.w;
    Ws[0][wc + 0][wr] = wv0.x; Ws[0][wc + 1][wr] = wv0.y;
    Ws[0][wc + 2][wr] = wv0.z; Ws[0][wc + 3][wr] = wv0.w;
    Ws[1][wc + 0][wr] = wv1.x; Ws[1][wc + 1][wr] = wv1.y;
    Ws[1][wc + 2][wr] = wv1.z; Ws[1][wc + 3][wr] = wv1.w;
    __syncthreads();
    if (k0 < 240) {
      a0  = *(const float4*)(arow + k0 + 16);
      a1  = *(const float4*)(arow + k0 + 20);
      wv0 = *(const float4*)(w0row + k0 + 16);
      wv1 = *(const float4*)(w1row + k0 + 16);
    }
#pragma unroll
    for (int k = 0; k < 16; ++k) {
      const float4 a0v = *(const float4*)&As[k][ty << 3];
      const float4 a1v = *(const float4*)&As[k][(ty << 3) + 4];
      const float am[8] = {a0v.x, a0v.y, a0v.z, a0v.w, a1v.x, a1v.y, a1v.z, a1v.w};
#pragma unroll
      for (int s = 0; s < 2; ++s) {
        const float4 wv = *(const float4*)&Ws[s][k][tx << 2];
#pragma unroll
        for (int i = 0; i < 8; ++i) {
          acc[s][i][0] += am[i] * wv.x;
          acc[s][i][1] += am[i] * wv.y;
          acc[s][i][2] += am[i] * wv.z;
          acc[s][i][3] += am[i] * wv.w;
        }
      }
    }
    __syncthreads();
  }
  const int cn = bn + (tx << 2);
  const float4 bg = *(const float4*)(b2 + cn);
  const float4 bp = *(const float4*)(b2 + 256 + cn);
#pragma unroll
  for (int i = 0; i < 8; ++i) {
    const size_t row = ((size_t)(bm + (ty << 3) + i)) << 8;
    float4 o;
    o.x = acc[0][i][0] + bg.x; o.y = acc[0][i][1] + bg.y;
    o.z = acc[0][i][2] + bg.z; o.w = acc[0][i][3] + bg.w;
    *(float4*)(Cg + row + cn) = o;
    o.x = acc[1][i][0] + bp.x; o.y = acc[1][i][1] + bp.y;
    o.z = acc[1][i][2] + bp.z; o.w = acc[1][i][3] + bp.w;
    *(float4*)(Cp + row + cn) = o;
  }
}

// ---------------------------------------------------------------------------
// gates GEMM (M=512, N=1024 interleaved i,f,g,o per unit, K=512 = [x|h])
// + fused LSTM epilogue. BM=16, BN=64, BK=32 -> 512 blocks (2/CU).
// (exact round-2-verified version)
// ---------------------------------------------------------------------------
__global__ __launch_bounds__(256) void gates_lstm_k(
    const float* __restrict__ x, const float* __restrict__ hin,
    const float* __restrict__ Wcat, const float* __restrict__ bcat,
    const float* __restrict__ cin, float* __restrict__ cnew,
    float* __restrict__ hnew)
{
  __shared__ __align__(16) float As[16][36];   // [m][k]
  __shared__ __align__(16) float Ws[32][68];   // [k][n]
  const int bn = blockIdx.x << 6;
  const int bm = blockIdx.y << 4;
  const int t  = threadIdx.x;
  const int ty = t >> 4, tx = t & 15;
  const int ar = t >> 4, ak = (t & 15) << 1;   // A staging: one float2
  const int wr = t >> 2, wk = (t & 3) << 3;    // W staging: two float4
  const float* wrow = Wcat + ((size_t)(bn + wr) << 9);
  const int arow = bm + ar;
  float acc0 = 0.f, acc1 = 0.f, acc2 = 0.f, acc3 = 0.f;
  for (int k0 = 0; k0 < 512; k0 += 32) {
    const int kk = k0 + ak;
    float2 av;
    if (kk < 256) av = *(const float2*)(x   + ((size_t)arow << 8) + kk);
    else          av = *(const float2*)(hin + ((size_t)arow << 8) + (kk - 256));
    const float4 w0 = *(const float4*)(wrow + k0 + wk);
    const float4 w1 = *(const float4*)(wrow + k0 + wk + 4);
    *(float2*)&As[ar][ak] = av;
    Ws[wk + 0][wr] = w0.x; Ws[wk + 1][wr] = w0.y; Ws[wk + 2][wr] = w0.z; Ws[wk + 3][wr] = w0.w;
    Ws[wk + 4][wr] = w1.x; Ws[wk + 5][wr] = w1.y; Ws[wk + 6][wr] = w1.z; Ws[wk + 7][wr] = w1.w;
    __syncthreads();
#pragma unroll
    for (int k = 0; k < 32; ++k) {
      const float a  = As[ty][k];
      const float4 w = *(const float4*)&Ws[k][tx << 2];
      acc0 += a * w.x; acc1 += a * w.y; acc2 += a * w.z; acc3 += a * w.w;
    }
    __syncthreads();
  }
  const float4 bb = *(const float4*)(bcat + bn + (tx << 2));
  const int jc = (bn >> 2) + tx;
  const int m  = bm + ty;
  const float ig = fsigm(acc0 + bb.x);
  const float fg = fsigm(acc1 + bb.y);
  const float gg = ftanh(acc2 + bb.z);
  const float og = fsigm(acc3 + bb.w);
  const float c  = fg * cin[(m << 8) + jc] + ig * gg;
  const float h  = og * ftanh(c);
  cnew[(m << 8) + jc] = c;
  hnew[(m << 8) + jc] = h;
}

// ---------------------------------------------------------------------------
// Fused per-step attention (round-2 arithmetic, bitwise-identical).
// NEW: e2g / e2p staged into ONE shared 64KB LDS buffer via async
// global_load_lds, issued so the vmcnt(0)+barrier drain overlaps the qg /
// qp matvec phases. Score phases read pure LDS (kills L3 latency exposure).
// part[512] aliases glp rows 0-1 (lifetimes disjoint) -> LDS 78.4KB, 2/CU.
// ---------------------------------------------------------------------------
__global__ __launch_bounds__(512) void step_attn_k(
    const float* __restrict__ h, const float* __restrict__ e2g,
    const float* __restrict__ e2p, const float* __restrict__ Wq1T4,
    const float* __restrict__ Wqp4, const float* __restrict__ qcour,
    const float* __restrict__ bqp, const float* __restrict__ vg,
    const float* __restrict__ vp, unsigned long long* __restrict__ mask,
    int* __restrict__ idxb, const float* __restrict__ emb,
    float* __restrict__ out_logp, float* __restrict__ out_sel,
    float* __restrict__ xb, int t)
{
  const int b = blockIdx.x, tid = threadIdx.x;
  __shared__ __align__(16) float hs[256], qgs[256], qps[256], gls[256];
  __shared__ __align__(16) float vgs[256], vps[256];
  __shared__ __align__(16) float glp[8][256];   // rows 0-1 also serve as part[512]
  __shared__ __align__(16) float eps[64][256];  // staged e2g, then e2p
  __shared__ float us[64], mxs[8], zws[8];
  __shared__ unsigned long long ms;
  __shared__ int bsel;
  float* part = &glp[0][0];
  if (tid < 256) {
    hs[tid]  = h[(b << 8) + tid];
    vgs[tid] = vg[tid];
    vps[tid] = vp[tid];
  }
  if (tid == 0) {
    unsigned long long m = mask[b];
    if (t > 0) {
      int s = idxb[b]; if (s < 0) s = 0;
      m |= (1ULL << s);
      if (m == ~0ULL) m &= ~(1ULL << 63);
      mask[b] = m;
    }
    ms = m;
  }
  __syncthreads();                               // B1
  const unsigned long long mm = ms;
  const int w = tid >> 6, lane = tid & 63;
  const int o = tid & 255, kh = tid >> 8;

  // issue async e2g -> eps (8 rows/wave); drains at B2 (overlaps qg matvec)
  {
    const float* gb = e2g + ((size_t)b << 8) + (lane << 2);
#pragma unroll
    for (int li = 0; li < 8; ++li) {
      const int l = (w << 3) + li;
      GLOAD_LDS16(gb + ((size_t)l << 17), &eps[l][0]);
    }
  }

  // phase 0: qg[o] = qcour[b,o] + sum_k Wq1[o][k] * h[b,k]  (split-k x2)
  {
    float acc = (kh == 0) ? qcour[(b << 8) + o] : 0.f;
    const float4* wp = (const float4*)Wq1T4 + o;
    const int kc0 = kh << 5;
#pragma unroll 8
    for (int kc = kc0; kc < kc0 + 32; ++kc) {
      const float4 wv = wp[kc << 8];
      const float4 h4 = *(const float4*)&hs[kc << 2];
      acc += wv.x * h4.x + wv.y * h4.y + wv.z * h4.z + wv.w * h4.w;
    }
    part[tid] = acc;
  }
  __syncthreads();                               // B2 (e2g resident)
  if (tid < 256) qgs[tid] = part[tid] + part[tid + 256];
  __syncthreads();                               // B3

  // scores_g from LDS + online-softmax accumulation of gl (8 l per wave)
  {
    const float4 q4 = *(const float4*)&qgs[lane << 2];
    const float4 v4 = *(const float4*)&vgs[lane << 2];
    float g0 = 0.f, g1 = 0.f, g2 = 0.f, g3 = 0.f;
    float mxw = -1e30f, zw = 0.f;
    for (int li = 0; li < 8; ++li) {
      const int l = (w << 3) + li;
      const float4 e4 = *(const float4*)&eps[l][lane << 2];
      float s = v4.x * ftanh(q4.x + e4.x) + v4.y * ftanh(q4.y + e4.y)
              + v4.z * ftanh(q4.z + e4.z) + v4.w * ftanh(q4.w + e4.w);
#pragma unroll
      for (int off = 32; off; off >>= 1) s += __shfl_xor(s, off, 64);
      if (!((mm >> l) & 1ULL)) {          // wave-uniform branch
        const float nm   = fmaxf(mxw, s);
        const float corr = __expf(mxw - nm);   // 0 on first hit (mxw=-1e30)
        const float wl   = __expf(s - nm);
        zw = zw * corr + wl;
        g0 = g0 * corr + wl * e4.x; g1 = g1 * corr + wl * e4.y;
        g2 = g2 * corr + wl * e4.z; g3 = g3 * corr + wl * e4.w;
        mxw = nm;
      }
    }
    glp[w][(lane << 2) + 0] = g0; glp[w][(lane << 2) + 1] = g1;
    glp[w][(lane << 2) + 2] = g2; glp[w][(lane << 2) + 3] = g3;
    if (lane == 0) { mxs[w] = mxw; zws[w] = zw; }
  }
  __syncthreads();                               // B4 (eps free for reuse)
  if (tid < 256) {
    float MX = mxs[0];
#pragma unroll
    for (int ww = 1; ww < 8; ++ww) MX = fmaxf(MX, mxs[ww]);
    float Z = 0.f, go = 0.f;
#pragma unroll
    for (int ww = 0; ww < 8; ++ww) {
      const float sc = __expf(mxs[ww] - MX);   // 0 for all-masked waves
      Z  += sc * zws[ww];
      go += sc * glp[ww][tid];
    }
    gls[tid] = go / Z;
  }
  // issue async e2p -> eps; drains at B5 (overlaps combine + qp matvec)
  {
    const float* gb = e2p + ((size_t)b << 8) + (lane << 2);
#pragma unroll
    for (int li = 0; li < 8; ++li) {
      const int l = (w << 3) + li;
      GLOAD_LDS16(gb + ((size_t)l << 17), &eps[l][0]);
    }
  }
  __syncthreads();                               // B5 (gls ready; e2p resident)

  // qp[o] = bqp[o] + sum_k Wqp[o][k] * gl[k]  (split-k x2)
  {
    float acc = (kh == 0) ? bqp[o] : 0.f;
    const float4* wp = (const float4*)Wqp4 + o;
    const int kc0 = kh << 5;
#pragma unroll 8
    for (int kc = kc0; kc < kc0 + 32; ++kc) {
      const float4 wv = wp[kc << 8];
      const float4 h4 = *(const float4*)&gls[kc << 2];
      acc += wv.x * h4.x + wv.y * h4.y + wv.z * h4.z + wv.w * h4.w;
    }
    part[tid] = acc;
  }
  __syncthreads();                               // B6
  if (tid < 256) qps[tid] = part[tid] + part[tid + 256];
  __syncthreads();                               // B7

  // scores_p from LDS, 10*tanh, mask -> us
  {
    const float4 q4 = *(const float4*)&qps[lane << 2];
    const float4 v4 = *(const float4*)&vps[lane << 2];
    for (int li = 0; li < 8; ++li) {
      const int l = (w << 3) + li;
      const float4 e4 = *(const float4*)&eps[l][lane << 2];
      float s = v4.x * ftanh(q4.x + e4.x) + v4.y * ftanh(q4.y + e4.y)
              + v4.z * ftanh(q4.z + e4.z) + v4.w * ftanh(q4.w + e4.w);
#pragma unroll
      for (int off = 32; off; off >>= 1) s += __shfl_xor(s, off, 64);
      if (lane == 0) us[l] = ((mm >> l) & 1ULL) ? NEGV : 10.0f * ftanh(s);
    }
  }
  __syncthreads();
  if (tid < 64) {
    const float xv = us[tid];
    float mx = xv;
#pragma unroll
    for (int off = 32; off; off >>= 1) mx = fmaxf(mx, __shfl_xor(mx, off, 64));
    const float sh = xv - mx;
    const float ev = __expf(sh);
    float sum = ev;
#pragma unroll
    for (int off = 32; off; off >>= 1) sum += __shfl_xor(sum, off, 64);
    const float lp = sh - __logf(sum);
    out_logp[((size_t)b << 12) + (t << 6) + tid] = lp;
    float bv = lp; int bi = tid;
#pragma unroll
    for (int off = 32; off; off >>= 1) {
      const float ov = __shfl_xor(bv, off, 64);
      const int   oi = __shfl_xor(bi, off, 64);
      if (ov > bv || (ov == bv && oi < bi)) { bv = ov; bi = oi; }
    }
    if (tid == 0) { idxb[b] = bi; out_sel[(b << 6) + t] = (float)bi; bsel = bi; }
  }
  __syncthreads();
  if (tid < 256) xb[(b << 8) + tid] = emb[(((size_t)(bsel << 9) + b) << 8) + tid];
}

// ---------------------------------------------------------------------------
// setup kernels
// ---------------------------------------------------------------------------
__global__ __launch_bounds__(256) void init_k(
    const float* __restrict__ dec, const float* __restrict__ h0,
    const float* __restrict__ c0, float* __restrict__ xb,
    float* __restrict__ hb, float* __restrict__ cb,
    unsigned long long* __restrict__ mask, int* __restrict__ idxb)
{
  const int i = blockIdx.x * 256 + threadIdx.x;
  xb[i] = dec[i]; hb[i] = h0[i]; cb[i] = c0[i];
  if (i < 512) { mask[i] = 0ULL; idxb[i] = -1; }
}

// Wcat[n][k], n=4*j+p interleaved (p in {i,f,g,o}), k = [x-part | h-part]
__global__ __launch_bounds__(256) void prep_wcat_k(
    const float* __restrict__ Wih, const float* __restrict__ Whh,
    const float* __restrict__ bih, const float* __restrict__ bhh,
    float* __restrict__ Wcat, float* __restrict__ bcat)
{
  const int id = blockIdx.x * 256 + threadIdx.x;
  const int n = id >> 9, k = id & 511;
  const int r = ((n & 3) << 8) + (n >> 2);
  Wcat[id] = (k < 256) ? Wih[(r << 8) + k] : Whh[(r << 8) + (k - 256)];
  if (id < 1024) {
    const int rr = ((id & 3) << 8) + (id >> 2);
    bcat[id] = bih[rr] + bhh[rr];
  }
}

// Wfused = Wq_g @ Wm (256x320), bfused = Wq_g @ bm + bq_g
__global__ __launch_bounds__(256) void prep_wfused_k(
    const float* __restrict__ Wqg, const float* __restrict__ Wm,
    const float* __restrict__ bm, const float* __restrict__ bqg,
    float* __restrict__ Wf, float* __restrict__ bf)
{
  const int id = blockIdx.x * 256 + threadIdx.x;  // 81920
  const int o = id / 320, j = id % 320;
  float acc = 0.f;
  for (int tt = 0; tt < 256; ++tt) acc += Wqg[(o << 8) + tt] * Wm[tt * 320 + j];
  Wf[id] = acc;
  if (id < 256) {
    float a2 = 0.f;
    for (int tt = 0; tt < 256; ++tt) a2 += Wqg[(id << 8) + tt] * bm[tt];
    bf[id] = a2 + bqg[id];
  }
}

// Wq1T4: packed transpose of Wfused[:, :256] for coalesced float4 matvec.
__global__ __launch_bounds__(256) void prep_wq1t4_k(
    const float* __restrict__ Wf, float* __restrict__ Wq1T4)
{
  const int id = blockIdx.x * 256 + threadIdx.x;  // 65536
  const int k = id >> 8, o = id & 255;
  Wq1T4[((k >> 2) << 10) + (o << 2) + (k & 3)] = Wf[o * 320 + k];
}

// Wqp4: packed transpose of raw Wqp for coalesced float4 matvec.
__global__ __launch_bounds__(256) void prep_wqp4_k(
    const float* __restrict__ Wqp, float* __restrict__ Wqp4)
{
  const int id = blockIdx.x * 256 + threadIdx.x;  // 65536
  const int k = id >> 8, o = id & 255;
  Wqp4[((k >> 2) << 10) + (o << 2) + (k & 3)] = Wqp[(o << 8) + k];
}

// qcour[b,o] = bfused[o] + sum_{k<64} Wfused[o][256+k] * cour[b][k]
__global__ __launch_bounds__(256) void prep_qcour_k(
    const float* __restrict__ Wf, const float* __restrict__ bf,
    const float* __restrict__ cour, float* __restrict__ qcour)
{
  const int b = blockIdx.x, o = threadIdx.x;
  __shared__ float cs[64];
  if (o < 64) cs[o] = cour[(b << 6) + o];
  __syncthreads();
  float acc = bf[o];
#pragma unroll 8
  for (int k = 0; k < 64; ++k) acc += Wf[o * 320 + 256 + k] * cs[k];
  qcour[(b << 8) + o] = acc;
}

// W2 rows 0..255 = Wrg, rows 256..511 = Wrp; b2 = {brg | brp}
__global__ __launch_bounds__(256) void prep_w2copy_k(
    const float* __restrict__ Wrg, const float* __restrict__ Wrp,
    const float* __restrict__ brg, const float* __restrict__ brp,
    float* __restrict__ W2, float* __restrict__ b2)
{
  const int id = blockIdx.x * 256 + threadIdx.x;   // 131072
  W2[id] = (id < 65536) ? Wrg[id] : Wrp[id - 65536];
  if (id < 256) b2[id] = brg[id];
  else if (id < 512) b2[id] = brp[id - 256];
}

// ---------------------------------------------------------------------------
extern "C" void kernel_launch(void* const* d_in, const int* in_sizes, int n_in,
                              void* d_out, int out_size, void* d_ws, size_t ws_size,
                              hipStream_t stream)
{
  const float* dec   = (const float*)d_in[0];
  const float* emb   = (const float*)d_in[1];
  const float* h0    = (const float*)d_in[2];
  const float* c0    = (const float*)d_in[3];
  const float* ctxin = (const float*)d_in[4];
  const float* cour  = (const float*)d_in[5];
  const float* Wih   = (const float*)d_in[7];
  const float* Whh   = (const float*)d_in[8];
  const float* bih   = (const float*)d_in[9];
  const float* bhh   = (const float*)d_in[10];
  const float* Wm    = (const float*)d_in[11];
  const float* bm    = (const float*)d_in[12];
  const float* Wqp   = (const float*)d_in[13];
  const float* bqp   = (const float*)d_in[14];
  const float* Wrp   = (const float*)d_in[15];
  const float* brp   = (const float*)d_in[16];
  const float* vp    = (const float*)d_in[17];
  const float* Wqg   = (const float*)d_in[18];
  const float* bqg   = (const float*)d_in[19];
  const float* Wrg   = (const float*)d_in[20];
  const float* brg   = (const float*)d_in[21];
  const float* vg    = (const float*)d_in[22];

  float* ws = (float*)d_ws;
  float* e2g    = ws + 0;         // 8388608
  float* e2p    = ws + 8388608;   // 8388608
  float* W2     = ws + 16777216;  // 131072
  float* b2     = ws + 16908288;  // 512
  float* Wcat   = ws + 16908800;  // 524288
  float* bcat   = ws + 17433088;  // 1024
  float* Wfused = ws + 17434112;  // 81920
  float* bfused = ws + 17516032;  // 256
  float* Wq1T4  = ws + 17516288;  // 65536
  float* Wqp4   = ws + 17581824;  // 65536
  float* qcour  = ws + 17647360;  // 131072
  float* hb0    = ws + 17778432;  // 131072
  float* hb1    = ws + 17909504;  // 131072
  float* cb0    = ws + 18040576;  // 131072
  float* cb1    = ws + 18171648;  // 131072
  float* xb     = ws + 18302720;  // 131072
  unsigned long long* maskb = (unsigned long long*)(ws + 18433792); // 512 u64
  int* idxb     = (int*)(ws + 18434816);                            // 512

  float* out_logp = (float*)d_out;            // [B][64][64]
  float* out_sel  = (float*)d_out + 2097152;  // [B][64]

  // ---- setup ----
  init_k<<<512, 256, 0, stream>>>(dec, h0, c0, xb, hb0, cb0, maskb, idxb);
  prep_wcat_k<<<2048, 256, 0, stream>>>(Wih, Whh, bih, bhh, Wcat, bcat);
  prep_wfused_k<<<320, 256, 0, stream>>>(Wqg, Wm, bm, bqg, Wfused, bfused);
  prep_wq1t4_k<<<256, 256, 0, stream>>>(Wfused, Wq1T4);
  prep_wqp4_k<<<256, 256, 0, stream>>>(Wqp, Wqp4);
  prep_qcour_k<<<512, 256, 0, stream>>>(Wfused, bfused, cour, qcour);
  prep_w2copy_k<<<512, 256, 0, stream>>>(Wrg, Wrp, brg, brp, W2, b2);
  gemm2_k<<<dim3(256, 4), 256, 0, stream>>>(ctxin, W2, b2, e2g, e2p);

  // ---- 64 sequential steps, 2 kernels each ----
  for (int t = 0; t < 64; ++t) {
    float* hcur = (t & 1) ? hb1 : hb0;
    float* hnew = (t & 1) ? hb0 : hb1;
    float* ccur = (t & 1) ? cb1 : cb0;
    float* cnew = (t & 1) ? cb0 : cb1;
    gates_lstm_k<<<dim3(16, 32), 256, 0, stream>>>(xb, hcur, Wcat, bcat,
                                                   ccur, cnew, hnew);
    step_attn_k<<<512, 512, 0, stream>>>(hnew, e2g, e2p, Wq1T4, Wqp4, qcour,
                                         bqp, vg, vp, maskb, idxb, emb,
                                         out_logp, out_sel, xb, t);
  }
}

// Round 8
// 2975.106 us; speedup vs baseline: 1.2208x; 1.1372x over previous
//
#include <hip/hip_runtime.h>
#include <cstdint>
#include <cstddef>

#define NEGV -1000000000.0f

// ---------- fast device math (fp32, argmax-safe) ----------
__device__ __forceinline__ float fsigm(float x) {
  return 1.0f / (1.0f + __expf(-x));
}
__device__ __forceinline__ float ftanh(float x) {
  x = fminf(x, 30.0f);
  const float e = __expf(2.0f * x);
  return (e - 1.0f) / (e + 1.0f);
}

// ---------------------------------------------------------------------------
// Fused setup GEMM: both context projections in one pass (shared A reads).
// grid(256,4): blockIdx.x = M-tile (fast dim) so the 4 N-tiles sharing one
// A-panel land on the same XCD -> L2 hit. Register double-buffered K-loop.
// (verified round 3/4: 115 us, FETCH 58 MB)
// ---------------------------------------------------------------------------
__global__ __launch_bounds__(256, 2) void gemm2_k(
    const float* __restrict__ A0, const float* __restrict__ W2,
    const float* __restrict__ b2, float* __restrict__ Cg,
    float* __restrict__ Cp)
{
  __shared__ float As[16][136];     // [k][m]
  __shared__ float Ws[2][16][72];   // [s][k][n]
  const int bm = blockIdx.x << 7;   // fast dim
  const int bn = blockIdx.y << 6;
  const int t  = threadIdx.x;
  const int ty = t >> 4, tx = t & 15;
  const int ar = t >> 1, ac = (t & 1) << 3;   // A staging: 2 float4
  const int wr = t >> 2, wc = (t & 3) << 2;   // W staging: 1 float4 per s
  const float* arow = A0 + (size_t)(bm + ar) * 256 + ac;
  const float* w0row = W2 + (size_t)(bn + wr) * 256 + wc;
  const float* w1row = W2 + (size_t)(256 + bn + wr) * 256 + wc;
  float acc[2][8][4] = {};
  float4 a0 = *(const float4*)(arow + 0);
  float4 a1 = *(const float4*)(arow + 4);
  float4 wv0 = *(const float4*)(w0row + 0);
  float4 wv1 = *(const float4*)(w1row + 0);
  for (int k0 = 0; k0 < 256; k0 += 16) {
    As[ac + 0][ar] = a0.x; As[ac + 1][ar] = a0.y; As[ac + 2][ar] = a0.z; As[ac + 3][ar] = a0.w;
    As[ac + 4][ar] = a1.x; As[ac + 5][ar] = a1.y; As[ac + 6][ar] = a1.z; As[ac + 7][ar] = a1.w;
    Ws[0][wc + 0][wr] = wv0.x; Ws[0][wc + 1][wr] = wv0.y;
    Ws[0][wc + 2][wr] = wv0.z; Ws[0][wc + 3][wr] = wv0.w;
    Ws[1][wc + 0][wr] = wv1.x; Ws[1][wc + 1][wr] = wv1.y;
    Ws[1][wc + 2][wr] = wv1.z; Ws[1][wc + 3][wr] = wv1.w;
    __syncthreads();
    if (k0 < 240) {
      a0  = *(const float4*)(arow + k0 + 16);
      a1  = *(const float4*)(arow + k0 + 20);
      wv0 = *(const float4*)(w0row + k0 + 16);
      wv1 = *(const float4*)(w1row + k0 + 16);
    }
#pragma unroll
    for (int k = 0; k < 16; ++k) {
      const float4 a0v = *(const float4*)&As[k][ty << 3];
      const float4 a1v = *(const float4*)&As[k][(ty << 3) + 4];
      const float am[8] = {a0v.x, a0v.y, a0v.z, a0v.w, a1v.x, a1v.y, a1v.z, a1v.w};
#pragma unroll
      for (int s = 0; s < 2; ++s) {
        const float4 wv = *(const float4*)&Ws[s][k][tx << 2];
#pragma unroll
        for (int i = 0; i < 8; ++i) {
          acc[s][i][0] += am[i] * wv.x;
          acc[s][i][1] += am[i] * wv.y;
          acc[s][i][2] += am[i] * wv.z;
          acc[s][i][3] += am[i] * wv.w;
        }
      }
    }
    __syncthreads();
  }
  const int cn = bn + (tx << 2);
  const float4 bg = *(const float4*)(b2 + cn);
  const float4 bp = *(const float4*)(b2 + 256 + cn);
#pragma unroll
  for (int i = 0; i < 8; ++i) {
    const size_t row = ((size_t)(bm + (ty << 3) + i)) << 8;
    float4 o;
    o.x = acc[0][i][0] + bg.x; o.y = acc[0][i][1] + bg.y;
    o.z = acc[0][i][2] + bg.z; o.w = acc[0][i][3] + bg.w;
    *(float4*)(Cg + row + cn) = o;
    o.x = acc[1][i][0] + bp.x; o.y = acc[1][i][1] + bp.y;
    o.z = acc[1][i][2] + bp.z; o.w = acc[1][i][3] + bp.w;
    *(float4*)(Cp + row + cn) = o;
  }
}

// ---------------------------------------------------------------------------
// gates GEMM (M=512, N=1024 interleaved i,f,g,o per unit, K=512 = [x|h])
// + fused LSTM epilogue. BM=16, BN=64, BK=32 -> 512 blocks (2/CU).
// (exact round-2-verified version)
// ---------------------------------------------------------------------------
__global__ __launch_bounds__(256) void gates_lstm_k(
    const float* __restrict__ x, const float* __restrict__ hin,
    const float* __restrict__ Wcat, const float* __restrict__ bcat,
    const float* __restrict__ cin, float* __restrict__ cnew,
    float* __restrict__ hnew)
{
  __shared__ __align__(16) float As[16][36];   // [m][k]
  __shared__ __align__(16) float Ws[32][68];   // [k][n]
  const int bn = blockIdx.x << 6;
  const int bm = blockIdx.y << 4;
  const int t  = threadIdx.x;
  const int ty = t >> 4, tx = t & 15;
  const int ar = t >> 4, ak = (t & 15) << 1;   // A staging: one float2
  const int wr = t >> 2, wk = (t & 3) << 3;    // W staging: two float4
  const float* wrow = Wcat + ((size_t)(bn + wr) << 9);
  const int arow = bm + ar;
  float acc0 = 0.f, acc1 = 0.f, acc2 = 0.f, acc3 = 0.f;
  for (int k0 = 0; k0 < 512; k0 += 32) {
    const int kk = k0 + ak;
    float2 av;
    if (kk < 256) av = *(const float2*)(x   + ((size_t)arow << 8) + kk);
    else          av = *(const float2*)(hin + ((size_t)arow << 8) + (kk - 256));
    const float4 w0 = *(const float4*)(wrow + k0 + wk);
    const float4 w1 = *(const float4*)(wrow + k0 + wk + 4);
    *(float2*)&As[ar][ak] = av;
    Ws[wk + 0][wr] = w0.x; Ws[wk + 1][wr] = w0.y; Ws[wk + 2][wr] = w0.z; Ws[wk + 3][wr] = w0.w;
    Ws[wk + 4][wr] = w1.x; Ws[wk + 5][wr] = w1.y; Ws[wk + 6][wr] = w1.z; Ws[wk + 7][wr] = w1.w;
    __syncthreads();
#pragma unroll
    for (int k = 0; k < 32; ++k) {
      const float a  = As[ty][k];
      const float4 w = *(const float4*)&Ws[k][tx << 2];
      acc0 += a * w.x; acc1 += a * w.y; acc2 += a * w.z; acc3 += a * w.w;
    }
    __syncthreads();
  }
  const float4 bb = *(const float4*)(bcat + bn + (tx << 2));
  const int jc = (bn >> 2) + tx;
  const int m  = bm + ty;
  const float ig = fsigm(acc0 + bb.x);
  const float fg = fsigm(acc1 + bb.y);
  const float gg = ftanh(acc2 + bb.z);
  const float og = fsigm(acc3 + bb.w);
  const float c  = fg * cin[(m << 8) + jc] + ig * gg;
  const float h  = og * ftanh(c);
  cnew[(m << 8) + jc] = c;
  hnew[(m << 8) + jc] = h;
}

// ---------------------------------------------------------------------------
// Fused per-step attention (round-2 arithmetic, bitwise-identical results).
// Masked l's are skipped ENTIRELY in both score passes (load + 256 tanh
// + shuffle reduce). l is wave-uniform inside the loops -> no divergence.
// Masked l contributes nothing to gl (guard already existed) and NEGV to us.
// Average ~49% of score-phase work eliminated across the 64 steps.
// ---------------------------------------------------------------------------
__global__ __launch_bounds__(512) void step_attn_k(
    const float* __restrict__ h, const float* __restrict__ e2g,
    const float* __restrict__ e2p, const float* __restrict__ Wq1T4,
    const float* __restrict__ Wqp4, const float* __restrict__ qcour,
    const float* __restrict__ bqp, const float* __restrict__ vg,
    const float* __restrict__ vp, unsigned long long* __restrict__ mask,
    int* __restrict__ idxb, const float* __restrict__ emb,
    float* __restrict__ out_logp, float* __restrict__ out_sel,
    float* __restrict__ xb, int t)
{
  const int b = blockIdx.x, tid = threadIdx.x;
  __shared__ __align__(16) float hs[256], qgs[256], qps[256], gls[256];
  __shared__ __align__(16) float vgs[256], vps[256];
  __shared__ __align__(16) float glp[8][256];
  __shared__ __align__(16) float part[512];
  __shared__ float us[64], mxs[8], zws[8];
  __shared__ unsigned long long ms;
  __shared__ int bsel;
  if (tid < 256) {
    hs[tid]  = h[(b << 8) + tid];
    vgs[tid] = vg[tid];
    vps[tid] = vp[tid];
  }
  if (tid == 0) {
    unsigned long long m = mask[b];
    if (t > 0) {
      int s = idxb[b]; if (s < 0) s = 0;
      m |= (1ULL << s);
      if (m == ~0ULL) m &= ~(1ULL << 63);
      mask[b] = m;
    }
    ms = m;
  }
  __syncthreads();
  const unsigned long long mm = ms;
  const int w = tid >> 6, lane = tid & 63;
  const int o = tid & 255, kh = tid >> 8;

  // phase 0: qg[o] = qcour[b,o] + sum_k Wq1[o][k] * h[b,k]  (split-k x2)
  {
    float acc = (kh == 0) ? qcour[(b << 8) + o] : 0.f;
    const float4* wp = (const float4*)Wq1T4 + o;
    const int kc0 = kh << 5;
#pragma unroll 8
    for (int kc = kc0; kc < kc0 + 32; ++kc) {
      const float4 wv = wp[kc << 8];
      const float4 h4 = *(const float4*)&hs[kc << 2];
      acc += wv.x * h4.x + wv.y * h4.y + wv.z * h4.z + wv.w * h4.w;
    }
    part[tid] = acc;
  }
  __syncthreads();
  if (tid < 256) qgs[tid] = part[tid] + part[tid + 256];
  __syncthreads();

  // scores_g over e2g + online-softmax accumulation of gl (8 l per wave);
  // masked l skipped entirely (wave-uniform branch, zero contribution).
  {
    const float4 q4 = *(const float4*)&qgs[lane << 2];
    const float4 v4 = *(const float4*)&vgs[lane << 2];
    const float* ebase = e2g + ((size_t)b << 8) + (lane << 2);
    float g0 = 0.f, g1 = 0.f, g2 = 0.f, g3 = 0.f;
    float mxw = -1e30f, zw = 0.f;
    for (int li = 0; li < 8; ++li) {
      const int l = (w << 3) + li;
      if ((mm >> l) & 1ULL) continue;   // masked: no load, no compute
      const float4 e4 = *(const float4*)(ebase + ((size_t)l << 17));
      float s = v4.x * ftanh(q4.x + e4.x) + v4.y * ftanh(q4.y + e4.y)
              + v4.z * ftanh(q4.z + e4.z) + v4.w * ftanh(q4.w + e4.w);
#pragma unroll
      for (int off = 32; off; off >>= 1) s += __shfl_xor(s, off, 64);
      {
        const float nm   = fmaxf(mxw, s);
        const float corr = __expf(mxw - nm);   // 0 on first hit (mxw=-1e30)
        const float wl   = __expf(s - nm);
        zw = zw * corr + wl;
        g0 = g0 * corr + wl * e4.x; g1 = g1 * corr + wl * e4.y;
        g2 = g2 * corr + wl * e4.z; g3 = g3 * corr + wl * e4.w;
        mxw = nm;
      }
    }
    glp[w][(lane << 2) + 0] = g0; glp[w][(lane << 2) + 1] = g1;
    glp[w][(lane << 2) + 2] = g2; glp[w][(lane << 2) + 3] = g3;
    if (lane == 0) { mxs[w] = mxw; zws[w] = zw; }
  }
  __syncthreads();
  if (tid < 256) {
    float MX = mxs[0];
#pragma unroll
    for (int ww = 1; ww < 8; ++ww) MX = fmaxf(MX, mxs[ww]);
    float Z = 0.f, go = 0.f;
#pragma unroll
    for (int ww = 0; ww < 8; ++ww) {
      const float sc = __expf(mxs[ww] - MX);   // 0 for all-masked waves
      Z  += sc * zws[ww];
      go += sc * glp[ww][tid];
    }
    gls[tid] = go / Z;
  }
  __syncthreads();

  // qp[o] = bqp[o] + sum_k Wqp[o][k] * gl[k]  (split-k x2)
  {
    float acc = (kh == 0) ? bqp[o] : 0.f;
    const float4* wp = (const float4*)Wqp4 + o;
    const int kc0 = kh << 5;
#pragma unroll 8
    for (int kc = kc0; kc < kc0 + 32; ++kc) {
      const float4 wv = wp[kc << 8];
      const float4 h4 = *(const float4*)&gls[kc << 2];
      acc += wv.x * h4.x + wv.y * h4.y + wv.z * h4.z + wv.w * h4.w;
    }
    part[tid] = acc;
  }
  __syncthreads();
  if (tid < 256) qps[tid] = part[tid] + part[tid + 256];
  __syncthreads();

  // scores_p over e2p, 10*tanh, mask -> us; masked l skipped entirely.
  {
    const float4 q4 = *(const float4*)&qps[lane << 2];
    const float4 v4 = *(const float4*)&vps[lane << 2];
    const float* ebase = e2p + ((size_t)b << 8) + (lane << 2);
    for (int li = 0; li < 8; ++li) {
      const int l = (w << 3) + li;
      if ((mm >> l) & 1ULL) {           // masked: constant output
        if (lane == 0) us[l] = NEGV;
        continue;
      }
      const float4 e4 = *(const float4*)(ebase + ((size_t)l << 17));
      float s = v4.x * ftanh(q4.x + e4.x) + v4.y * ftanh(q4.y + e4.y)
              + v4.z * ftanh(q4.z + e4.z) + v4.w * ftanh(q4.w + e4.w);
#pragma unroll
      for (int off = 32; off; off >>= 1) s += __shfl_xor(s, off, 64);
      if (lane == 0) us[l] = 10.0f * ftanh(s);
    }
  }
  __syncthreads();
  if (tid < 64) {
    const float xv = us[tid];
    float mx = xv;
#pragma unroll
    for (int off = 32; off; off >>= 1) mx = fmaxf(mx, __shfl_xor(mx, off, 64));
    const float sh = xv - mx;
    const float ev = __expf(sh);
    float sum = ev;
#pragma unroll
    for (int off = 32; off; off >>= 1) sum += __shfl_xor(sum, off, 64);
    const float lp = sh - __logf(sum);
    out_logp[((size_t)b << 12) + (t << 6) + tid] = lp;
    float bv = lp; int bi = tid;
#pragma unroll
    for (int off = 32; off; off >>= 1) {
      const float ov = __shfl_xor(bv, off, 64);
      const int   oi = __shfl_xor(bi, off, 64);
      if (ov > bv || (ov == bv && oi < bi)) { bv = ov; bi = oi; }
    }
    if (tid == 0) { idxb[b] = bi; out_sel[(b << 6) + t] = (float)bi; bsel = bi; }
  }
  __syncthreads();
  if (tid < 256) xb[(b << 8) + tid] = emb[(((size_t)(bsel << 9) + b) << 8) + tid];
}

// ---------------------------------------------------------------------------
// setup kernels
// ---------------------------------------------------------------------------
__global__ __launch_bounds__(256) void init_k(
    const float* __restrict__ dec, const float* __restrict__ h0,
    const float* __restrict__ c0, float* __restrict__ xb,
    float* __restrict__ hb, float* __restrict__ cb,
    unsigned long long* __restrict__ mask, int* __restrict__ idxb)
{
  const int i = blockIdx.x * 256 + threadIdx.x;
  xb[i] = dec[i]; hb[i] = h0[i]; cb[i] = c0[i];
  if (i < 512) { mask[i] = 0ULL; idxb[i] = -1; }
}

// Wcat[n][k], n=4*j+p interleaved (p in {i,f,g,o}), k = [x-part | h-part]
__global__ __launch_bounds__(256) void prep_wcat_k(
    const float* __restrict__ Wih, const float* __restrict__ Whh,
    const float* __restrict__ bih, const float* __restrict__ bhh,
    float* __restrict__ Wcat, float* __restrict__ bcat)
{
  const int id = blockIdx.x * 256 + threadIdx.x;
  const int n = id >> 9, k = id & 511;
  const int r = ((n & 3) << 8) + (n >> 2);
  Wcat[id] = (k < 256) ? Wih[(r << 8) + k] : Whh[(r << 8) + (k - 256)];
  if (id < 1024) {
    const int rr = ((id & 3) << 8) + (id >> 2);
    bcat[id] = bih[rr] + bhh[rr];
  }
}

// Wfused = Wq_g @ Wm (256x320), bfused = Wq_g @ bm + bq_g
__global__ __launch_bounds__(256) void prep_wfused_k(
    const float* __restrict__ Wqg, const float* __restrict__ Wm,
    const float* __restrict__ bm, const float* __restrict__ bqg,
    float* __restrict__ Wf, float* __restrict__ bf)
{
  const int id = blockIdx.x * 256 + threadIdx.x;  // 81920
  const int o = id / 320, j = id % 320;
  float acc = 0.f;
  for (int tt = 0; tt < 256; ++tt) acc += Wqg[(o << 8) + tt] * Wm[tt * 320 + j];
  Wf[id] = acc;
  if (id < 256) {
    float a2 = 0.f;
    for (int tt = 0; tt < 256; ++tt) a2 += Wqg[(id << 8) + tt] * bm[tt];
    bf[id] = a2 + bqg[id];
  }
}

// Wq1T4: packed transpose of Wfused[:, :256] for coalesced float4 matvec.
__global__ __launch_bounds__(256) void prep_wq1t4_k(
    const float* __restrict__ Wf, float* __restrict__ Wq1T4)
{
  const int id = blockIdx.x * 256 + threadIdx.x;  // 65536
  const int k = id >> 8, o = id & 255;
  Wq1T4[((k >> 2) << 10) + (o << 2) + (k & 3)] = Wf[o * 320 + k];
}

// Wqp4: packed transpose of raw Wqp for coalesced float4 matvec.
__global__ __launch_bounds__(256) void prep_wqp4_k(
    const float* __restrict__ Wqp, float* __restrict__ Wqp4)
{
  const int id = blockIdx.x * 256 + threadIdx.x;  // 65536
  const int k = id >> 8, o = id & 255;
  Wqp4[((k >> 2) << 10) + (o << 2) + (k & 3)] = Wqp[(o << 8) + k];
}

// qcour[b,o] = bfused[o] + sum_{k<64} Wfused[o][256+k] * cour[b][k]
__global__ __launch_bounds__(256) void prep_qcour_k(
    const float* __restrict__ Wf, const float* __restrict__ bf,
    const float* __restrict__ cour, float* __restrict__ qcour)
{
  const int b = blockIdx.x, o = threadIdx.x;
  __shared__ float cs[64];
  if (o < 64) cs[o] = cour[(b << 6) + o];
  __syncthreads();
  float acc = bf[o];
#pragma unroll 8
  for (int k = 0; k < 64; ++k) acc += Wf[o * 320 + 256 + k] * cs[k];
  qcour[(b << 8) + o] = acc;
}

// W2 rows 0..255 = Wrg, rows 256..511 = Wrp; b2 = {brg | brp}
__global__ __launch_bounds__(256) void prep_w2copy_k(
    const float* __restrict__ Wrg, const float* __restrict__ Wrp,
    const float* __restrict__ brg, const float* __restrict__ brp,
    float* __restrict__ W2, float* __restrict__ b2)
{
  const int id = blockIdx.x * 256 + threadIdx.x;   // 131072
  W2[id] = (id < 65536) ? Wrg[id] : Wrp[id - 65536];
  if (id < 256) b2[id] = brg[id];
  else if (id < 512) b2[id] = brp[id - 256];
}

// ---------------------------------------------------------------------------
extern "C" void kernel_launch(void* const* d_in, const int* in_sizes, int n_in,
                              void* d_out, int out_size, void* d_ws, size_t ws_size,
                              hipStream_t stream)
{
  const float* dec   = (const float*)d_in[0];
  const float* emb   = (const float*)d_in[1];
  const float* h0    = (const float*)d_in[2];
  const float* c0    = (const float*)d_in[3];
  const float* ctxin = (const float*)d_in[4];
  const float* cour  = (const float*)d_in[5];
  const float* Wih   = (const float*)d_in[7];
  const float* Whh   = (const float*)d_in[8];
  const float* bih   = (const float*)d_in[9];
  const float* bhh   = (const float*)d_in[10];
  const float* Wm    = (const float*)d_in[11];
  const float* bm    = (const float*)d_in[12];
  const float* Wqp   = (const float*)d_in[13];
  const float* bqp   = (const float*)d_in[14];
  const float* Wrp   = (const float*)d_in[15];
  const float* brp   = (const float*)d_in[16];
  const float* vp    = (const float*)d_in[17];
  const float* Wqg   = (const float*)d_in[18];
  const float* bqg   = (const float*)d_in[19];
  const float* Wrg   = (const float*)d_in[20];
  const float* brg   = (const float*)d_in[21];
  const float* vg    = (const float*)d_in[22];

  float* ws = (float*)d_ws;
  float* e2g    = ws + 0;         // 8388608
  float* e2p    = ws + 8388608;   // 8388608
  float* W2     = ws + 16777216;  // 131072
  float* b2     = ws + 16908288;  // 512
  float* Wcat   = ws + 16908800;  // 524288
  float* bcat   = ws + 17433088;  // 1024
  float* Wfused = ws + 17434112;  // 81920
  float* bfused = ws + 17516032;  // 256
  float* Wq1T4  = ws + 17516288;  // 65536
  float* Wqp4   = ws + 17581824;  // 65536
  float* qcour  = ws + 17647360;  // 131072
  float* hb0    = ws + 17778432;  // 131072
  float* hb1    = ws + 17909504;  // 131072
  float* cb0    = ws + 18040576;  // 131072
  float* cb1    = ws + 18171648;  // 131072
  float* xb     = ws + 18302720;  // 131072
  unsigned long long* maskb = (unsigned long long*)(ws + 18433792); // 512 u64
  int* idxb     = (int*)(ws + 18434816);                            // 512

  float* out_logp = (float*)d_out;            // [B][64][64]
  float* out_sel  = (float*)d_out + 2097152;  // [B][64]

  // ---- setup ----
  init_k<<<512, 256, 0, stream>>>(dec, h0, c0, xb, hb0, cb0, maskb, idxb);
  prep_wcat_k<<<2048, 256, 0, stream>>>(Wih, Whh, bih, bhh, Wcat, bcat);
  prep_wfused_k<<<320, 256, 0, stream>>>(Wqg, Wm, bm, bqg, Wfused, bfused);
  prep_wq1t4_k<<<256, 256, 0, stream>>>(Wfused, Wq1T4);
  prep_wqp4_k<<<256, 256, 0, stream>>>(Wqp, Wqp4);
  prep_qcour_k<<<512, 256, 0, stream>>>(Wfused, bfused, cour, qcour);
  prep_w2copy_k<<<512, 256, 0, stream>>>(Wrg, Wrp, brg, brp, W2, b2);
  gemm2_k<<<dim3(256, 4), 256, 0, stream>>>(ctxin, W2, b2, e2g, e2p);

  // ---- 64 sequential steps, 2 kernels each ----
  for (int t = 0; t < 64; ++t) {
    float* hcur = (t & 1) ? hb1 : hb0;
    float* hnew = (t & 1) ? hb0 : hb1;
    float* ccur = (t & 1) ? cb1 : cb0;
    float* cnew = (t & 1) ? cb0 : cb1;
    gates_lstm_k<<<dim3(16, 32), 256, 0, stream>>>(xb, hcur, Wcat, bcat,
                                                   ccur, cnew, hnew);
    step_attn_k<<<512, 512, 0, stream>>>(hnew, e2g, e2p, Wq1T4, Wqp4, qcour,
                                         bqp, vg, vp, maskb, idxb, emb,
                                         out_logp, out_sel, xb, t);
  }
}

// Round 9
// 2868.571 us; speedup vs baseline: 1.2662x; 1.0371x over previous
//
#include <hip/hip_runtime.h>
#include <cstdint>
#include <cstddef>

#define NEGV -1000000000.0f

// ---------- fast device math (fp32, argmax-safe) ----------
__device__ __forceinline__ float fsigm(float x) {
  return 1.0f / (1.0f + __expf(-x));
}
__device__ __forceinline__ float ftanh(float x) {
  x = fminf(x, 30.0f);
  const float e = __expf(2.0f * x);
  return (e - 1.0f) / (e + 1.0f);
}

// ---------------------------------------------------------------------------
// Fused setup GEMM: both context projections in one pass (shared A reads).
// grid(256,4): blockIdx.x = M-tile (fast dim) so the 4 N-tiles sharing one
// A-panel land on the same XCD -> L2 hit. Register double-buffered K-loop.
// (verified rounds 3/4/8: ~115 us, FETCH 58 MB)
// ---------------------------------------------------------------------------
__global__ __launch_bounds__(256, 2) void gemm2_k(
    const float* __restrict__ A0, const float* __restrict__ W2,
    const float* __restrict__ b2, float* __restrict__ Cg,
    float* __restrict__ Cp)
{
  __shared__ float As[16][136];     // [k][m]
  __shared__ float Ws[2][16][72];   // [s][k][n]
  const int bm = blockIdx.x << 7;   // fast dim
  const int bn = blockIdx.y << 6;
  const int t  = threadIdx.x;
  const int ty = t >> 4, tx = t & 15;
  const int ar = t >> 1, ac = (t & 1) << 3;   // A staging: 2 float4
  const int wr = t >> 2, wc = (t & 3) << 2;   // W staging: 1 float4 per s
  const float* arow = A0 + (size_t)(bm + ar) * 256 + ac;
  const float* w0row = W2 + (size_t)(bn + wr) * 256 + wc;
  const float* w1row = W2 + (size_t)(256 + bn + wr) * 256 + wc;
  float acc[2][8][4] = {};
  float4 a0 = *(const float4*)(arow + 0);
  float4 a1 = *(const float4*)(arow + 4);
  float4 wv0 = *(const float4*)(w0row + 0);
  float4 wv1 = *(const float4*)(w1row + 0);
  for (int k0 = 0; k0 < 256; k0 += 16) {
    As[ac + 0][ar] = a0.x; As[ac + 1][ar] = a0.y; As[ac + 2][ar] = a0.z; As[ac + 3][ar] = a0.w;
    As[ac + 4][ar] = a1.x; As[ac + 5][ar] = a1.y; As[ac + 6][ar] = a1.z; As[ac + 7][ar] = a1.w;
    Ws[0][wc + 0][wr] = wv0.x; Ws[0][wc + 1][wr] = wv0.y;
    Ws[0][wc + 2][wr] = wv0.z; Ws[0][wc + 3][wr] = wv0.w;
    Ws[1][wc + 0][wr] = wv1.x; Ws[1][wc + 1][wr] = wv1.y;
    Ws[1][wc + 2][wr] = wv1.z; Ws[1][wc + 3][wr] = wv1.w;
    __syncthreads();
    if (k0 < 240) {
      a0  = *(const float4*)(arow + k0 + 16);
      a1  = *(const float4*)(arow + k0 + 20);
      wv0 = *(const float4*)(w0row + k0 + 16);
      wv1 = *(const float4*)(w1row + k0 + 16);
    }
#pragma unroll
    for (int k = 0; k < 16; ++k) {
      const float4 a0v = *(const float4*)&As[k][ty << 3];
      const float4 a1v = *(const float4*)&As[k][(ty << 3) + 4];
      const float am[8] = {a0v.x, a0v.y, a0v.z, a0v.w, a1v.x, a1v.y, a1v.z, a1v.w};
#pragma unroll
      for (int s = 0; s < 2; ++s) {
        const float4 wv = *(const float4*)&Ws[s][k][tx << 2];
#pragma unroll
        for (int i = 0; i < 8; ++i) {
          acc[s][i][0] += am[i] * wv.x;
          acc[s][i][1] += am[i] * wv.y;
          acc[s][i][2] += am[i] * wv.z;
          acc[s][i][3] += am[i] * wv.w;
        }
      }
    }
    __syncthreads();
  }
  const int cn = bn + (tx << 2);
  const float4 bg = *(const float4*)(b2 + cn);
  const float4 bp = *(const float4*)(b2 + 256 + cn);
#pragma unroll
  for (int i = 0; i < 8; ++i) {
    const size_t row = ((size_t)(bm + (ty << 3) + i)) << 8;
    float4 o;
    o.x = acc[0][i][0] + bg.x; o.y = acc[0][i][1] + bg.y;
    o.z = acc[0][i][2] + bg.z; o.w = acc[0][i][3] + bg.w;
    *(float4*)(Cg + row + cn) = o;
    o.x = acc[1][i][0] + bp.x; o.y = acc[1][i][1] + bp.y;
    o.z = acc[1][i][2] + bp.z; o.w = acc[1][i][3] + bp.w;
    *(float4*)(Cp + row + cn) = o;
  }
}

// ---------------------------------------------------------------------------
// gates GEMM (M=512, N=1024 interleaved i,f,g,o per unit, K=512 = [x|h])
// + fused LSTM epilogue. BM=16, BN=64, BK=32 -> 512 blocks (2/CU).
// (exact round-2-verified version)
// ---------------------------------------------------------------------------
__global__ __launch_bounds__(256) void gates_lstm_k(
    const float* __restrict__ x, const float* __restrict__ hin,
    const float* __restrict__ Wcat, const float* __restrict__ bcat,
    const float* __restrict__ cin, float* __restrict__ cnew,
    float* __restrict__ hnew)
{
  __shared__ __align__(16) float As[16][36];   // [m][k]
  __shared__ __align__(16) float Ws[32][68];   // [k][n]
  const int bn = blockIdx.x << 6;
  const int bm = blockIdx.y << 4;
  const int t  = threadIdx.x;
  const int ty = t >> 4, tx = t & 15;
  const int ar = t >> 4, ak = (t & 15) << 1;   // A staging: one float2
  const int wr = t >> 2, wk = (t & 3) << 3;    // W staging: two float4
  const float* wrow = Wcat + ((size_t)(bn + wr) << 9);
  const int arow = bm + ar;
  float acc0 = 0.f, acc1 = 0.f, acc2 = 0.f, acc3 = 0.f;
  for (int k0 = 0; k0 < 512; k0 += 32) {
    const int kk = k0 + ak;
    float2 av;
    if (kk < 256) av = *(const float2*)(x   + ((size_t)arow << 8) + kk);
    else          av = *(const float2*)(hin + ((size_t)arow << 8) + (kk - 256));
    const float4 w0 = *(const float4*)(wrow + k0 + wk);
    const float4 w1 = *(const float4*)(wrow + k0 + wk + 4);
    *(float2*)&As[ar][ak] = av;
    Ws[wk + 0][wr] = w0.x; Ws[wk + 1][wr] = w0.y; Ws[wk + 2][wr] = w0.z; Ws[wk + 3][wr] = w0.w;
    Ws[wk + 4][wr] = w1.x; Ws[wk + 5][wr] = w1.y; Ws[wk + 6][wr] = w1.z; Ws[wk + 7][wr] = w1.w;
    __syncthreads();
#pragma unroll
    for (int k = 0; k < 32; ++k) {
      const float a  = As[ty][k];
      const float4 w = *(const float4*)&Ws[k][tx << 2];
      acc0 += a * w.x; acc1 += a * w.y; acc2 += a * w.z; acc3 += a * w.w;
    }
    __syncthreads();
  }
  const float4 bb = *(const float4*)(bcat + bn + (tx << 2));
  const int jc = (bn >> 2) + tx;
  const int m  = bm + ty;
  const float ig = fsigm(acc0 + bb.x);
  const float fg = fsigm(acc1 + bb.y);
  const float gg = ftanh(acc2 + bb.z);
  const float og = fsigm(acc3 + bb.w);
  const float c  = fg * cin[(m << 8) + jc] + ig * gg;
  const float h  = og * ftanh(c);
  cnew[(m << 8) + jc] = c;
  hnew[(m << 8) + jc] = h;
}

// ---------------------------------------------------------------------------
// Fused per-step attention (round-2 arithmetic for every unmasked l).
// Mask-skip (round-8 verified) + NEW: compacted unmasked-l list lidx[cnt],
// strided across the 8 waves -> per-wave score work balanced to ceil(cnt/8)
// instead of max-over-waves of the scattered mask distribution.
// scores_p per-l results bitwise-identical; scores_g per-wave partials
// regroup (fp32 reorder only, same terms).
// ---------------------------------------------------------------------------
__global__ __launch_bounds__(512) void step_attn_k(
    const float* __restrict__ h, const float* __restrict__ e2g,
    const float* __restrict__ e2p, const float* __restrict__ Wq1T4,
    const float* __restrict__ Wqp4, const float* __restrict__ qcour,
    const float* __restrict__ bqp, const float* __restrict__ vg,
    const float* __restrict__ vp, unsigned long long* __restrict__ mask,
    int* __restrict__ idxb, const float* __restrict__ emb,
    float* __restrict__ out_logp, float* __restrict__ out_sel,
    float* __restrict__ xb, int t)
{
  const int b = blockIdx.x, tid = threadIdx.x;
  __shared__ __align__(16) float hs[256], qgs[256], qps[256], gls[256];
  __shared__ __align__(16) float vgs[256], vps[256];
  __shared__ __align__(16) float glp[8][256];
  __shared__ __align__(16) float part[512];
  __shared__ float us[64], mxs[8], zws[8];
  __shared__ int lidx[64];
  __shared__ int lcnt;
  __shared__ unsigned long long ms;
  __shared__ int bsel;
  if (tid < 256) {
    hs[tid]  = h[(b << 8) + tid];
    vgs[tid] = vg[tid];
    vps[tid] = vp[tid];
  }
  if (tid >= 256 && tid < 320) us[tid - 256] = NEGV;   // masked l -> NEGV
  if (tid == 0) {
    unsigned long long m = mask[b];
    if (t > 0) {
      int s = idxb[b]; if (s < 0) s = 0;
      m |= (1ULL << s);
      if (m == ~0ULL) m &= ~(1ULL << 63);
      mask[b] = m;
    }
    ms = m;
    int c = 0;
    for (int l = 0; l < 64; ++l)
      if (!((m >> l) & 1ULL)) lidx[c++] = l;
    lcnt = c;                                  // >= 1 (full mask prevented)
  }
  __syncthreads();
  const int cnt = lcnt;
  const int w = tid >> 6, lane = tid & 63;
  const int o = tid & 255, kh = tid >> 8;

  // phase 0: qg[o] = qcour[b,o] + sum_k Wq1[o][k] * h[b,k]  (split-k x2)
  {
    float acc = (kh == 0) ? qcour[(b << 8) + o] : 0.f;
    const float4* wp = (const float4*)Wq1T4 + o;
    const int kc0 = kh << 5;
#pragma unroll 8
    for (int kc = kc0; kc < kc0 + 32; ++kc) {
      const float4 wv = wp[kc << 8];
      const float4 h4 = *(const float4*)&hs[kc << 2];
      acc += wv.x * h4.x + wv.y * h4.y + wv.z * h4.z + wv.w * h4.w;
    }
    part[tid] = acc;
  }
  __syncthreads();
  if (tid < 256) qgs[tid] = part[tid] + part[tid + 256];
  __syncthreads();

  // scores_g over compacted unmasked l's (strided across waves) +
  // online-softmax accumulation of gl.
  {
    const float4 q4 = *(const float4*)&qgs[lane << 2];
    const float4 v4 = *(const float4*)&vgs[lane << 2];
    const float* ebase = e2g + ((size_t)b << 8) + (lane << 2);
    float g0 = 0.f, g1 = 0.f, g2 = 0.f, g3 = 0.f;
    float mxw = -1e30f, zw = 0.f;
    for (int i = w; i < cnt; i += 8) {
      const int l = lidx[i];
      const float4 e4 = *(const float4*)(ebase + ((size_t)l << 17));
      float s = v4.x * ftanh(q4.x + e4.x) + v4.y * ftanh(q4.y + e4.y)
              + v4.z * ftanh(q4.z + e4.z) + v4.w * ftanh(q4.w + e4.w);
#pragma unroll
      for (int off = 32; off; off >>= 1) s += __shfl_xor(s, off, 64);
      const float nm   = fmaxf(mxw, s);
      const float corr = __expf(mxw - nm);   // 0 on first hit (mxw=-1e30)
      const float wl   = __expf(s - nm);
      zw = zw * corr + wl;
      g0 = g0 * corr + wl * e4.x; g1 = g1 * corr + wl * e4.y;
      g2 = g2 * corr + wl * e4.z; g3 = g3 * corr + wl * e4.w;
      mxw = nm;
    }
    glp[w][(lane << 2) + 0] = g0; glp[w][(lane << 2) + 1] = g1;
    glp[w][(lane << 2) + 2] = g2; glp[w][(lane << 2) + 3] = g3;
    if (lane == 0) { mxs[w] = mxw; zws[w] = zw; }
  }
  __syncthreads();
  if (tid < 256) {
    float MX = mxs[0];
#pragma unroll
    for (int ww = 1; ww < 8; ++ww) MX = fmaxf(MX, mxs[ww]);
    float Z = 0.f, go = 0.f;
#pragma unroll
    for (int ww = 0; ww < 8; ++ww) {
      const float sc = __expf(mxs[ww] - MX);   // 0 for item-less waves
      Z  += sc * zws[ww];
      go += sc * glp[ww][tid];
    }
    gls[tid] = go / Z;
  }
  __syncthreads();

  // qp[o] = bqp[o] + sum_k Wqp[o][k] * gl[k]  (split-k x2)
  {
    float acc = (kh == 0) ? bqp[o] : 0.f;
    const float4* wp = (const float4*)Wqp4 + o;
    const int kc0 = kh << 5;
#pragma unroll 8
    for (int kc = kc0; kc < kc0 + 32; ++kc) {
      const float4 wv = wp[kc << 8];
      const float4 h4 = *(const float4*)&gls[kc << 2];
      acc += wv.x * h4.x + wv.y * h4.y + wv.z * h4.z + wv.w * h4.w;
    }
    part[tid] = acc;
  }
  __syncthreads();
  if (tid < 256) qps[tid] = part[tid] + part[tid + 256];
  __syncthreads();

  // scores_p over compacted unmasked l's (strided), 10*tanh -> us
  // (us pre-filled with NEGV for masked l's).
  {
    const float4 q4 = *(const float4*)&qps[lane << 2];
    const float4 v4 = *(const float4*)&vps[lane << 2];
    const float* ebase = e2p + ((size_t)b << 8) + (lane << 2);
    for (int i = w; i < cnt; i += 8) {
      const int l = lidx[i];
      const float4 e4 = *(const float4*)(ebase + ((size_t)l << 17));
      float s = v4.x * ftanh(q4.x + e4.x) + v4.y * ftanh(q4.y + e4.y)
              + v4.z * ftanh(q4.z + e4.z) + v4.w * ftanh(q4.w + e4.w);
#pragma unroll
      for (int off = 32; off; off >>= 1) s += __shfl_xor(s, off, 64);
      if (lane == 0) us[l] = 10.0f * ftanh(s);
    }
  }
  __syncthreads();
  if (tid < 64) {
    const float xv = us[tid];
    float mx = xv;
#pragma unroll
    for (int off = 32; off; off >>= 1) mx = fmaxf(mx, __shfl_xor(mx, off, 64));
    const float sh = xv - mx;
    const float ev = __expf(sh);
    float sum = ev;
#pragma unroll
    for (int off = 32; off; off >>= 1) sum += __shfl_xor(sum, off, 64);
    const float lp = sh - __logf(sum);
    out_logp[((size_t)b << 12) + (t << 6) + tid] = lp;
    float bv = lp; int bi = tid;
#pragma unroll
    for (int off = 32; off; off >>= 1) {
      const float ov = __shfl_xor(bv, off, 64);
      const int   oi = __shfl_xor(bi, off, 64);
      if (ov > bv || (ov == bv && oi < bi)) { bv = ov; bi = oi; }
    }
    if (tid == 0) { idxb[b] = bi; out_sel[(b << 6) + t] = (float)bi; bsel = bi; }
  }
  __syncthreads();
  if (tid < 256) xb[(b << 8) + tid] = emb[(((size_t)(bsel << 9) + b) << 8) + tid];
}

// ---------------------------------------------------------------------------
// setup kernels
// ---------------------------------------------------------------------------
__global__ __launch_bounds__(256) void init_k(
    const float* __restrict__ dec, const float* __restrict__ h0,
    const float* __restrict__ c0, float* __restrict__ xb,
    float* __restrict__ hb, float* __restrict__ cb,
    unsigned long long* __restrict__ mask, int* __restrict__ idxb)
{
  const int i = blockIdx.x * 256 + threadIdx.x;
  xb[i] = dec[i]; hb[i] = h0[i]; cb[i] = c0[i];
  if (i < 512) { mask[i] = 0ULL; idxb[i] = -1; }
}

// Wcat[n][k], n=4*j+p interleaved (p in {i,f,g,o}), k = [x-part | h-part]
__global__ __launch_bounds__(256) void prep_wcat_k(
    const float* __restrict__ Wih, const float* __restrict__ Whh,
    const float* __restrict__ bih, const float* __restrict__ bhh,
    float* __restrict__ Wcat, float* __restrict__ bcat)
{
  const int id = blockIdx.x * 256 + threadIdx.x;
  const int n = id >> 9, k = id & 511;
  const int r = ((n & 3) << 8) + (n >> 2);
  Wcat[id] = (k < 256) ? Wih[(r << 8) + k] : Whh[(r << 8) + (k - 256)];
  if (id < 1024) {
    const int rr = ((id & 3) << 8) + (id >> 2);
    bcat[id] = bih[rr] + bhh[rr];
  }
}

// Wfused = Wq_g @ Wm (256x320), bfused = Wq_g @ bm + bq_g
__global__ __launch_bounds__(256) void prep_wfused_k(
    const float* __restrict__ Wqg, const float* __restrict__ Wm,
    const float* __restrict__ bm, const float* __restrict__ bqg,
    float* __restrict__ Wf, float* __restrict__ bf)
{
  const int id = blockIdx.x * 256 + threadIdx.x;  // 81920
  const int o = id / 320, j = id % 320;
  float acc = 0.f;
  for (int tt = 0; tt < 256; ++tt) acc += Wqg[(o << 8) + tt] * Wm[tt * 320 + j];
  Wf[id] = acc;
  if (id < 256) {
    float a2 = 0.f;
    for (int tt = 0; tt < 256; ++tt) a2 += Wqg[(id << 8) + tt] * bm[tt];
    bf[id] = a2 + bqg[id];
  }
}

// Wq1T4: packed transpose of Wfused[:, :256] for coalesced float4 matvec.
__global__ __launch_bounds__(256) void prep_wq1t4_k(
    const float* __restrict__ Wf, float* __restrict__ Wq1T4)
{
  const int id = blockIdx.x * 256 + threadIdx.x;  // 65536
  const int k = id >> 8, o = id & 255;
  Wq1T4[((k >> 2) << 10) + (o << 2) + (k & 3)] = Wf[o * 320 + k];
}

// Wqp4: packed transpose of raw Wqp for coalesced float4 matvec.
__global__ __launch_bounds__(256) void prep_wqp4_k(
    const float* __restrict__ Wqp, float* __restrict__ Wqp4)
{
  const int id = blockIdx.x * 256 + threadIdx.x;  // 65536
  const int k = id >> 8, o = id & 255;
  Wqp4[((k >> 2) << 10) + (o << 2) + (k & 3)] = Wqp[(o << 8) + k];
}

// qcour[b,o] = bfused[o] + sum_{k<64} Wfused[o][256+k] * cour[b][k]
__global__ __launch_bounds__(256) void prep_qcour_k(
    const float* __restrict__ Wf, const float* __restrict__ bf,
    const float* __restrict__ cour, float* __restrict__ qcour)
{
  const int b = blockIdx.x, o = threadIdx.x;
  __shared__ float cs[64];
  if (o < 64) cs[o] = cour[(b << 6) + o];
  __syncthreads();
  float acc = bf[o];
#pragma unroll 8
  for (int k = 0; k < 64; ++k) acc += Wf[o * 320 + 256 + k] * cs[k];
  qcour[(b << 8) + o] = acc;
}

// W2 rows 0..255 = Wrg, rows 256..511 = Wrp; b2 = {brg | brp}
__global__ __launch_bounds__(256) void prep_w2copy_k(
    const float* __restrict__ Wrg, const float* __restrict__ Wrp,
    const float* __restrict__ brg, const float* __restrict__ brp,
    float* __restrict__ W2, float* __restrict__ b2)
{
  const int id = blockIdx.x * 256 + threadIdx.x;   // 131072
  W2[id] = (id < 65536) ? Wrg[id] : Wrp[id - 65536];
  if (id < 256) b2[id] = brg[id];
  else if (id < 512) b2[id] = brp[id - 256];
}

// ---------------------------------------------------------------------------
extern "C" void kernel_launch(void* const* d_in, const int* in_sizes, int n_in,
                              void* d_out, int out_size, void* d_ws, size_t ws_size,
                              hipStream_t stream)
{
  const float* dec   = (const float*)d_in[0];
  const float* emb   = (const float*)d_in[1];
  const float* h0    = (const float*)d_in[2];
  const float* c0    = (const float*)d_in[3];
  const float* ctxin = (const float*)d_in[4];
  const float* cour  = (const float*)d_in[5];
  const float* Wih   = (const float*)d_in[7];
  const float* Whh   = (const float*)d_in[8];
  const float* bih   = (const float*)d_in[9];
  const float* bhh   = (const float*)d_in[10];
  const float* Wm    = (const float*)d_in[11];
  const float* bm    = (const float*)d_in[12];
  const float* Wqp   = (const float*)d_in[13];
  const float* bqp   = (const float*)d_in[14];
  const float* Wrp   = (const float*)d_in[15];
  const float* brp   = (const float*)d_in[16];
  const float* vp    = (const float*)d_in[17];
  const float* Wqg   = (const float*)d_in[18];
  const float* bqg   = (const float*)d_in[19];
  const float* Wrg   = (const float*)d_in[20];
  const float* brg   = (const float*)d_in[21];
  const float* vg    = (const float*)d_in[22];

  float* ws = (float*)d_ws;
  float* e2g    = ws + 0;         // 8388608
  float* e2p    = ws + 8388608;   // 8388608
  float* W2     = ws + 16777216;  // 131072
  float* b2     = ws + 16908288;  // 512
  float* Wcat   = ws + 16908800;  // 524288
  float* bcat   = ws + 17433088;  // 1024
  float* Wfused = ws + 17434112;  // 81920
  float* bfused = ws + 17516032;  // 256
  float* Wq1T4  = ws + 17516288;  // 65536
  float* Wqp4   = ws + 17581824;  // 65536
  float* qcour  = ws + 17647360;  // 131072
  float* hb0    = ws + 17778432;  // 131072
  float* hb1    = ws + 17909504;  // 131072
  float* cb0    = ws + 18040576;  // 131072
  float* cb1    = ws + 18171648;  // 131072
  float* xb     = ws + 18302720;  // 131072
  unsigned long long* maskb = (unsigned long long*)(ws + 18433792); // 512 u64
  int* idxb     = (int*)(ws + 18434816);                            // 512

  float* out_logp = (float*)d_out;            // [B][64][64]
  float* out_sel  = (float*)d_out + 2097152;  // [B][64]

  // ---- setup ----
  init_k<<<512, 256, 0, stream>>>(dec, h0, c0, xb, hb0, cb0, maskb, idxb);
  prep_wcat_k<<<2048, 256, 0, stream>>>(Wih, Whh, bih, bhh, Wcat, bcat);
  prep_wfused_k<<<320, 256, 0, stream>>>(Wqg, Wm, bm, bqg, Wfused, bfused);
  prep_wq1t4_k<<<256, 256, 0, stream>>>(Wfused, Wq1T4);
  prep_wqp4_k<<<256, 256, 0, stream>>>(Wqp, Wqp4);
  prep_qcour_k<<<512, 256, 0, stream>>>(Wfused, bfused, cour, qcour);
  prep_w2copy_k<<<512, 256, 0, stream>>>(Wrg, Wrp, brg, brp, W2, b2);
  gemm2_k<<<dim3(256, 4), 256, 0, stream>>>(ctxin, W2, b2, e2g, e2p);

  // ---- 64 sequential steps, 2 kernels each ----
  for (int t = 0; t < 64; ++t) {
    float* hcur = (t & 1) ? hb1 : hb0;
    float* hnew = (t & 1) ? hb0 : hb1;
    float* ccur = (t & 1) ? cb1 : cb0;
    float* cnew = (t & 1) ? cb0 : cb1;
    gates_lstm_k<<<dim3(16, 32), 256, 0, stream>>>(xb, hcur, Wcat, bcat,
                                                   ccur, cnew, hnew);
    step_attn_k<<<512, 512, 0, stream>>>(hnew, e2g, e2p, Wq1T4, Wqp4, qcour,
                                         bqp, vg, vp, maskb, idxb, emb,
                                         out_logp, out_sel, xb, t);
  }
}